// Round 7
// baseline (18729.021 us; speedup 1.0000x reference)
//
#include <hip/hip_runtime.h>
#include <hip/hip_bf16.h>
#include <math.h>

typedef __hip_bfloat16 bf16;

#define T_TOK 196608   // B*N = 1024*192
#define NSEQ  192
#define DMODEL 256

__device__ __forceinline__ float cvt(float v){ return v; }
__device__ __forceinline__ float cvt(bf16 v){ return __bfloat162float(v); }

__device__ __forceinline__ float gelu_f(float x){
  const float k0 = 0.7978845608028654f; // sqrt(2/pi)
  return 0.5f*x*(1.0f + tanhf(k0*(x + 0.044715f*x*x*x)));
}

// ---- per-token LN stats (wave per token, 4 tokens/block) ------------------
__global__ __launch_bounds__(256) void ln_stats_kernel(
    const bf16* __restrict__ X, float* __restrict__ mu, float* __restrict__ rsd)
{
  int lane = threadIdx.x & 63, w = threadIdx.x >> 6;
  size_t t = (size_t)blockIdx.x * 4 + w;
  float x[4];
  #pragma unroll
  for (int j = 0; j < 4; j++) x[j] = cvt(X[t*DMODEL + lane + 64*j]);
  float s = x[0] + x[1] + x[2] + x[3];
  #pragma unroll
  for (int off = 32; off; off >>= 1) s += __shfl_xor(s, off, 64);
  float m = s * (1.f/256.f);
  float q = 0.f;
  #pragma unroll
  for (int j = 0; j < 4; j++){ float d = x[j] - m; q += d*d; }
  #pragma unroll
  for (int off = 32; off; off >>= 1) q += __shfl_xor(q, off, 64);
  if (lane == 0){ mu[t] = m; rsd[t] = rsqrtf(q*(1.f/256.f) + 1e-6f); }
}

// ---- x += delta; then LN stats of updated x -------------------------------
__global__ __launch_bounds__(256) void add_stats_kernel(
    bf16* __restrict__ X, const bf16* __restrict__ Dlt,
    float* __restrict__ mu, float* __restrict__ rsd)
{
  int lane = threadIdx.x & 63, w = threadIdx.x >> 6;
  size_t t = (size_t)blockIdx.x * 4 + w;
  float x[4];
  #pragma unroll
  for (int j = 0; j < 4; j++){
    int c = lane + 64*j;
    x[j] = cvt(X[t*DMODEL + c]) + cvt(Dlt[t*DMODEL + c]);
    X[t*DMODEL + c] = __float2bfloat16(x[j]);
  }
  float s = x[0] + x[1] + x[2] + x[3];
  #pragma unroll
  for (int off = 32; off; off >>= 1) s += __shfl_xor(s, off, 64);
  float m = s * (1.f/256.f);
  float q = 0.f;
  #pragma unroll
  for (int j = 0; j < 4; j++){ float d = x[j] - m; q += d*d; }
  #pragma unroll
  for (int off = 32; off; off >>= 1) q += __shfl_xor(q, off, 64);
  if (lane == 0){ mu[t] = m; rsd[t] = rsqrtf(q*(1.f/256.f) + 1e-6f); }
}

// ---- in-place: x = ln(x)*s+b + pos_embed  (block per token) ---------------
__global__ __launch_bounds__(256) void ln_pe_kernel(
    bf16* __restrict__ X, const float* __restrict__ s, const float* __restrict__ b)
{
  __shared__ float part[4];
  int t = blockIdx.x, d = threadIdx.x;
  int n = t % NSEQ;
  int lane = threadIdx.x & 63, w = threadIdx.x >> 6;
  float x = cvt(X[(size_t)t*DMODEL + d]);
  float v = x;
  #pragma unroll
  for (int off = 32; off; off >>= 1) v += __shfl_xor(v, off, 64);
  if (lane == 0) part[w] = v;
  __syncthreads();
  float mean = (part[0]+part[1]+part[2]+part[3]) * (1.f/256.f);
  float diff = x - mean;
  float vv = diff*diff;
  #pragma unroll
  for (int off = 32; off; off >>= 1) vv += __shfl_xor(vv, off, 64);
  __syncthreads();
  if (lane == 0) part[w] = vv;
  __syncthreads();
  float var = (part[0]+part[1]+part[2]+part[3]) * (1.f/256.f);
  float y = diff * rsqrtf(var + 1e-6f) * s[d] + b[d];
  float e = (float)(2*(d>>1)) / 256.f;
  float ang = (float)n * powf(10000.f, -e);
  y += (d & 1) ? cosf(ang) : sinf(ang);
  X[(size_t)t*DMODEL + d] = __float2bfloat16(y);
}

// ---- tiled GEMM, 128x128 tile, BK=16, 256 thr, 8x8 microtile --------------
// MODE 0: A[row*lda+k]    MODE 1: LN-fused A loader (A bf16)
template<int MODE, bool ADD, bool GELU, typename AT>
__global__ __launch_bounds__(256) void gemm(
    const AT* __restrict__ A, int lda,
    const float* __restrict__ mu, const float* __restrict__ rs,
    const float* __restrict__ lnS, const float* __restrict__ lnB,
    const float* __restrict__ W, int ldw, const float* __restrict__ bias,
    bf16* __restrict__ C, int ldc, int K)
{
  __shared__ float As[16][132];
  __shared__ float Bs[16][132];
  const int tid = threadIdx.x;
  const int tx = tid & 15, ty = tid >> 4;
  const int m0 = blockIdx.y * 128, n0 = blockIdx.x * 128;
  float acc[8][8] = {};

  for (int k0 = 0; k0 < K; k0 += 16){
    #pragma unroll
    for (int i = 0; i < 8; i++){
      int idx = i*256 + tid;
      int m = idx >> 4, k = idx & 15;
      int gk = k0 + k;
      float v = 0.f;
      if (gk < K){
        size_t row = (size_t)(m0 + m);
        if (MODE == 0) v = cvt(A[row * lda + gk]);
        else v = (cvt(A[row * lda + gk]) - mu[row]) * rs[row]
                 * lnS[gk] + lnB[gk];
      }
      As[k][m] = v;
    }
    #pragma unroll
    for (int i = 0; i < 8; i++){
      int idx = i*256 + tid;
      int k = idx >> 7, n = idx & 127;
      int gk = k0 + k;
      Bs[k][n] = (gk < K) ? W[(size_t)gk * ldw + (n0 + n)] : 0.f;
    }
    __syncthreads();
    #pragma unroll
    for (int kk = 0; kk < 16; kk++){
      const float4 a0 = *reinterpret_cast<const float4*>(&As[kk][ty*8]);
      const float4 a1 = *reinterpret_cast<const float4*>(&As[kk][ty*8+4]);
      const float4 b0 = *reinterpret_cast<const float4*>(&Bs[kk][tx*8]);
      const float4 b1 = *reinterpret_cast<const float4*>(&Bs[kk][tx*8+4]);
      const float a[8] = {a0.x,a0.y,a0.z,a0.w,a1.x,a1.y,a1.z,a1.w};
      const float b[8] = {b0.x,b0.y,b0.z,b0.w,b1.x,b1.y,b1.z,b1.w};
      #pragma unroll
      for (int i = 0; i < 8; i++)
        #pragma unroll
        for (int j = 0; j < 8; j++)
          acc[i][j] += a[i] * b[j];
    }
    __syncthreads();
  }

  #pragma unroll
  for (int i = 0; i < 8; i++){
    size_t m = (size_t)m0 + ty*8 + i;
    #pragma unroll
    for (int j = 0; j < 8; j++){
      int n = n0 + tx*8 + j;
      float r = acc[i][j] + bias[n];
      if (ADD) r += cvt(C[m * ldc + n]);
      if (GELU) r = gelu_f(r);
      C[m * ldc + n] = __float2bfloat16(r);
    }
  }
}

// ---- full-row GEMM (BM=64, BN=CPT*32) -------------------------------------
// MODE 2: concat(pts[row,0:K1] (f32), Xr[row,0:256] (bf16)) @ W  (skip layer)
// MODE 3: concat(Ft[row,0:256] (bf16), views[row/192,0:27] (f32)) @ W (rgb1)
template<int MODE, bool GELU, int CPT, typename T1, typename T2>
__global__ __launch_bounds__(256) void gemm_rowblk(
    const T1* __restrict__ A, const T2* __restrict__ A2,
    const float* __restrict__ W, const float* __restrict__ bias,
    bf16* __restrict__ C, int K, int K1)
{
  const int Nc = CPT*32;
  __shared__ float As[16][68];
  __shared__ float Bs[16][CPT*32];
  const int tid = threadIdx.x;
  const int tx = tid & 31, ty = tid >> 5;
  const size_t m0 = (size_t)blockIdx.x * 64;
  float acc[8][CPT] = {};

  for (int k0 = 0; k0 < K; k0 += 16){
    #pragma unroll
    for (int i = 0; i < 4; i++){
      int idx = i*256 + tid;
      int m = idx >> 4, kk = idx & 15;
      int gk = k0 + kk;
      float vv = 0.f;
      if (gk < K){
        size_t row = m0 + m;
        if (MODE == 2) vv = (gk < K1) ? cvt(A[row*K1 + gk]) : cvt(A2[row*256 + (gk-K1)]);
        else           vv = (gk < K1) ? cvt(A[row*256 + gk]) : cvt(A2[(row/NSEQ)*27 + (gk-K1)]);
      }
      As[kk][m] = vv;
    }
    #pragma unroll
    for (int i = 0; i < CPT*2; i++){
      int idx = i*256 + tid;
      int kk = idx / Nc, n = idx % Nc;
      int gk = k0 + kk;
      Bs[kk][n] = (gk < K) ? W[(size_t)gk*Nc + n] : 0.f;
    }
    __syncthreads();
    #pragma unroll
    for (int kk = 0; kk < 16; kk++){
      float a[8];
      #pragma unroll
      for (int i = 0; i < 8; i++) a[i] = As[kk][ty*8 + i];
      float b[CPT];
      #pragma unroll
      for (int j = 0; j < CPT; j++) b[j] = Bs[kk][tx*CPT + j];
      #pragma unroll
      for (int i = 0; i < 8; i++)
        #pragma unroll
        for (int j = 0; j < CPT; j++)
          acc[i][j] += a[i] * b[j];
    }
    __syncthreads();
  }
  #pragma unroll
  for (int i = 0; i < 8; i++){
    size_t m = m0 + ty*8 + i;
    #pragma unroll
    for (int j = 0; j < CPT; j++){
      int n = tx*CPT + j;
      float r = acc[i][j] + bias[n];
      if (GELU) r = gelu_f(r);
      C[m*256 + n] = __float2bfloat16(r);
    }
  }
}

// ---- simple fused windowed attention: one 8-token window per block --------
// grid (24, 1024). Everything through f32 LDS, thread = column.
__global__ __launch_bounds__(256) void attn_simple(
    const bf16* __restrict__ X, bf16* __restrict__ X2,
    const float* __restrict__ mu, const float* __restrict__ rs,
    const float* __restrict__ lnS, const float* __restrict__ lnB,
    const float* __restrict__ wq, const float* __restrict__ bq,
    const float* __restrict__ wk, const float* __restrict__ bk,
    const float* __restrict__ wv, const float* __restrict__ bv,
    const float* __restrict__ wo, const float* __restrict__ bo,
    int shift)
{
  __shared__ float ys[8][256];
  __shared__ float qs[8][256];
  __shared__ float ks[8][256];
  __shared__ float vs[8][256];
  __shared__ float sc[8][8][8];   // [h][q][k]
  const int c = threadIdx.x;
  const int w0 = blockIdx.x * 8;
  const size_t seqBase = (size_t)blockIdx.y * NSEQ;

  int srcRow[8];
  #pragma unroll
  for (int j = 0; j < 8; j++){
    int sn = w0 + j + shift; if (sn >= NSEQ) sn -= NSEQ;
    srcRow[j] = sn;
    size_t row = seqBase + sn;
    float x = cvt(X[row*256 + c]);
    ys[j][c] = (x - mu[row]) * rs[row] * lnS[c] + lnB[c];
  }
  __syncthreads();

  // q,k,v for this window: thread computes column c for all 8 tokens
  #pragma unroll 1
  for (int j = 0; j < 8; j++){
    float aq = bq[c], ak = bk[c], av = bv[c];
    for (int k = 0; k < 256; k++){
      float yv = ys[j][k];
      aq = fmaf(yv, wq[k*256+c], aq);
      ak = fmaf(yv, wk[k*256+c], ak);
      av = fmaf(yv, wv[k*256+c], av);
    }
    qs[j][c]=aq; ks[j][c]=ak; vs[j][c]=av;
  }
  __syncthreads();

  // scores: 512 (h,q,k) tuples over 256 threads x 2
  const float scale = 0.17677669529663687f; // 1/sqrt(32)
  #pragma unroll
  for (int r = 0; r < 2; r++){
    int idx = r*256 + c;
    int h = idx >> 6, qi = (idx >> 3) & 7, ki = idx & 7;
    float s = 0.f;
    #pragma unroll
    for (int d = 0; d < 32; d++) s += qs[qi][h*32+d] * ks[ki][h*32+d];
    sc[h][qi][ki] = s * scale;
  }
  __syncthreads();

  if (c < 64){
    int h = c >> 3, qi = c & 7;
    float mx = -1e30f;
    #pragma unroll
    for (int u = 0; u < 8; u++) mx = fmaxf(mx, sc[h][qi][u]);
    float e[8], sum = 0.f;
    #pragma unroll
    for (int u = 0; u < 8; u++){ e[u] = __expf(sc[h][qi][u] - mx); sum += e[u]; }
    float inv = 1.f / sum;
    #pragma unroll
    for (int u = 0; u < 8; u++) sc[h][qi][u] = e[u] * inv;
  }
  __syncthreads();

  // o = a @ v  (overwrite qs; qs fully consumed by score phase)
  {
    int h = c >> 5;
    #pragma unroll
    for (int j = 0; j < 8; j++){
      float o = 0.f;
      #pragma unroll
      for (int u = 0; u < 8; u++) o += sc[h][j][u] * vs[u][c];
      qs[j][c] = o;
    }
  }
  __syncthreads();

  // proj: po = o @ wo + bo, write to source rows (roll-back)
  #pragma unroll 1
  for (int j = 0; j < 8; j++){
    float a = bo[c];
    for (int k = 0; k < 256; k++) a = fmaf(qs[j][k], wo[k*256+c], a);
    X2[(seqBase + srcRow[j])*256 + c] = __float2bfloat16(a);
  }
}

// ---- alpha head with fused ln_f: one wave per token (f32 out) -------------
__global__ __launch_bounds__(256) void alpha_kernel(
    const bf16* __restrict__ X, const float* __restrict__ mu,
    const float* __restrict__ rs, const float* __restrict__ s,
    const float* __restrict__ b, const float* __restrict__ wa,
    const float* __restrict__ ba, float* __restrict__ out)
{
  int lane = threadIdx.x & 63, w = threadIdx.x >> 6;
  size_t t = (size_t)blockIdx.x * 4 + w;
  float m = mu[t], r = rs[t];
  float acc = 0.f;
  #pragma unroll
  for (int j = 0; j < 4; j++){
    int c = lane + 64*j;
    float y = (cvt(X[t*DMODEL + c]) - m) * r * s[c] + b[c];
    acc += y * wa[c];
  }
  #pragma unroll
  for (int off = 32; off; off >>= 1) acc += __shfl_down(acc, off, 64);
  if (lane == 0) out[t] = acc + ba[0];
}

// ---- rgb2: t1 stored with ld=256 (cols 0..127), @ (128,3) + b (f32 out) ---
__global__ __launch_bounds__(256) void rgb2_kernel(
    const bf16* __restrict__ T1, const float* __restrict__ w2,
    const float* __restrict__ b2, float* __restrict__ out)
{
  int lane = threadIdx.x & 63, w = threadIdx.x >> 6;
  size_t t = (size_t)blockIdx.x * 4 + w;
  float h0 = cvt(T1[t*256 + lane]);
  float h1 = cvt(T1[t*256 + 64 + lane]);
  float a0 = h0*w2[lane*3+0] + h1*w2[(lane+64)*3+0];
  float a1 = h0*w2[lane*3+1] + h1*w2[(lane+64)*3+1];
  float a2 = h0*w2[lane*3+2] + h1*w2[(lane+64)*3+2];
  #pragma unroll
  for (int off = 32; off; off >>= 1){
    a0 += __shfl_down(a0, off, 64);
    a1 += __shfl_down(a1, off, 64);
    a2 += __shfl_down(a2, off, 64);
  }
  if (lane == 0){
    out[t*3+0] = a0 + b2[0];
    out[t*3+1] = a1 + b2[1];
    out[t*3+2] = a2 + b2[2];
  }
}

extern "C" void kernel_launch(void* const* d_in, const int* in_sizes, int n_in,
                              void* d_out, int out_size, void* d_ws, size_t ws_size,
                              hipStream_t stream)
{
  (void)in_sizes; (void)n_in; (void)out_size;
  const float* pts     = (const float*)d_in[0];
  const float* views   = (const float*)d_in[1];
  const float* w_in    = (const float*)d_in[2];
  const float* b_in    = (const float*)d_in[3];
  const float* ln_in_s = (const float*)d_in[4];
  const float* ln_in_b = (const float*)d_in[5];
  const float* ln1_s   = (const float*)d_in[6];
  const float* ln1_b   = (const float*)d_in[7];
  const float* wq      = (const float*)d_in[8];
  const float* bq      = (const float*)d_in[9];
  const float* wk      = (const float*)d_in[10];
  const float* bk      = (const float*)d_in[11];
  const float* wv      = (const float*)d_in[12];
  const float* bv      = (const float*)d_in[13];
  const float* wo      = (const float*)d_in[14];
  const float* bo      = (const float*)d_in[15];
  const float* ln2_s   = (const float*)d_in[16];
  const float* ln2_b   = (const float*)d_in[17];
  const float* w_mlp1  = (const float*)d_in[18];
  const float* b_mlp1  = (const float*)d_in[19];
  const float* w_mlp2  = (const float*)d_in[20];
  const float* b_mlp2  = (const float*)d_in[21];
  const float* w_skip  = (const float*)d_in[22];
  const float* b_skip  = (const float*)d_in[23];
  const float* ln_f_s  = (const float*)d_in[24];
  const float* ln_f_b  = (const float*)d_in[25];
  const float* w_alpha = (const float*)d_in[26];
  const float* b_alpha = (const float*)d_in[27];
  const float* w_feat  = (const float*)d_in[28];
  const float* b_feat  = (const float*)d_in[29];
  const float* w_rgb1  = (const float*)d_in[30];
  const float* b_rgb1  = (const float*)d_in[31];
  const float* w_rgb2  = (const float*)d_in[32];
  const float* b_rgb2  = (const float*)d_in[33];

  const size_t SZ = (size_t)T_TOK * DMODEL * 2;        // 100,663,296 B
  const size_t NEED = 2*SZ + (size_t)2*T_TOK*4;        // ~203 MB
  if (ws_size < NEED) return;

  char* wsp = (char*)d_ws;
  bf16* xr = (bf16*)(wsp);
  bf16* x2 = (bf16*)(wsp + SZ);
  float* mu = (float*)(wsp + 2*SZ);
  float* rs = mu + T_TOK;

  float* out_rgb   = (float*)d_out;
  float* out_alpha = out_rgb + (size_t)T_TOK * 3;

  dim3 blk(256);
  dim3 g256(2, T_TOK/128);
  dim3 gRow(T_TOK/64);
  dim3 gTok(T_TOK);
  dim3 gStat(T_TOK/4);
  dim3 gAttn(24, 1024);

  const float* NF = nullptr;

  // x = pts @ w_in + b_in -> xr ; x = ln(x) + pe (in place)
  gemm<0,false,false,float><<<g256, blk, 0, stream>>>(pts, 63, NF, NF, NF, NF,
      w_in, 256, b_in, xr, 256, 63);
  ln_pe_kernel<<<gTok, blk, 0, stream>>>(xr, ln_in_s, ln_in_b);

  for (int i = 0; i < 2; i++){
    const int shift = (i == 1) ? 4 : 0;
    const float* wq_i = wq + (size_t)i*65536;
    const float* wk_i = wk + (size_t)i*65536;
    const float* wv_i = wv + (size_t)i*65536;
    const float* wo_i = wo + (size_t)i*65536;
    const float* w1_i = w_mlp1 + (size_t)i*65536;
    const float* w2_i = w_mlp2 + (size_t)i*65536;
    const float* ws_i = w_skip + (size_t)i*81664; // 319*256

    ln_stats_kernel<<<gStat, blk, 0, stream>>>(xr, mu, rs);
    attn_simple<<<gAttn, blk, 0, stream>>>(xr, x2, mu, rs,
        ln1_s + i*256, ln1_b + i*256,
        wq_i, bq + i*256, wk_i, bk + i*256, wv_i, bv + i*256,
        wo_i, bo + i*256, shift);
    add_stats_kernel<<<gStat, blk, 0, stream>>>(xr, x2, mu, rs);
    gemm<1,false,true ,bf16><<<g256, blk, 0, stream>>>(xr, 256, mu, rs,
        ln2_s + i*256, ln2_b + i*256, w1_i, 256, b_mlp1 + i*256, x2, 256, 256);
    gemm<0,true ,false,bf16><<<g256, blk, 0, stream>>>(x2, 256, NF, NF, NF, NF,
        w2_i, 256, b_mlp2 + i*256, xr, 256, 256);
    // x = gelu(concat(pts, x) @ w_skip + b_skip) -> x2, then swap (no in-place)
    gemm_rowblk<2,true,8,float,bf16><<<gRow, blk, 0, stream>>>(pts, xr, ws_i,
        b_skip + i*256, x2, 319, 63);
    bf16* tmp = xr; xr = x2; x2 = tmp;
  }

  // head
  ln_stats_kernel<<<gStat, blk, 0, stream>>>(xr, mu, rs);
  alpha_kernel<<<gStat, blk, 0, stream>>>(xr, mu, rs, ln_f_s, ln_f_b,
      w_alpha, b_alpha, out_alpha);
  // feature = ln_f(x) @ w_feat + b_feat -> x2
  gemm<1,false,false,bf16><<<g256, blk, 0, stream>>>(xr, 256, mu, rs,
      ln_f_s, ln_f_b, w_feat, 256, b_feat, x2, 256, 256);
  // t1 = gelu(concat(feature, views) @ w_rgb1 + b_rgb1) -> xr cols 0..127
  gemm_rowblk<3,true,4,bf16,float><<<gRow, blk, 0, stream>>>(x2, views, w_rgb1,
      b_rgb1, xr, 283, 256);
  rgb2_kernel<<<gStat, blk, 0, stream>>>(xr, w_rgb2, b_rgb2, out_rgb);
}

// Round 8
// 12641.015 us; speedup vs baseline: 1.4816x; 1.4816x over previous
//
#include <hip/hip_runtime.h>
#include <hip/hip_bf16.h>
#include <math.h>

typedef __hip_bfloat16 bf16;

#define T_TOK 196608   // B*N = 1024*192
#define NSEQ  192
#define DMODEL 256
#define CHUNKS 4
#define CHUNKM (T_TOK/CHUNKS)   // 49152 tokens = 256 sequences

__device__ __forceinline__ float cvt(float v){ return v; }
__device__ __forceinline__ float cvt(bf16 v){ return __bfloat162float(v); }

__device__ __forceinline__ float gelu_f(float x){
  const float k0 = 0.7978845608028654f; // sqrt(2/pi)
  return 0.5f*x*(1.0f + tanhf(k0*(x + 0.044715f*x*x*x)));
}

// ---- per-token LN stats (wave per token, 4 tokens/block) ------------------
__global__ __launch_bounds__(256) void ln_stats_kernel(
    const bf16* __restrict__ X, float* __restrict__ mu, float* __restrict__ rsd)
{
  int lane = threadIdx.x & 63, w = threadIdx.x >> 6;
  size_t t = (size_t)blockIdx.x * 4 + w;
  float x[4];
  #pragma unroll
  for (int j = 0; j < 4; j++) x[j] = cvt(X[t*DMODEL + lane + 64*j]);
  float s = x[0] + x[1] + x[2] + x[3];
  #pragma unroll
  for (int off = 32; off; off >>= 1) s += __shfl_xor(s, off, 64);
  float m = s * (1.f/256.f);
  float q = 0.f;
  #pragma unroll
  for (int j = 0; j < 4; j++){ float d = x[j] - m; q += d*d; }
  #pragma unroll
  for (int off = 32; off; off >>= 1) q += __shfl_xor(q, off, 64);
  if (lane == 0){ mu[t] = m; rsd[t] = rsqrtf(q*(1.f/256.f) + 1e-6f); }
}

// ---- in-place: x = ln(x)*s+b + pos_embed  (block per token) ---------------
__global__ __launch_bounds__(256) void ln_pe_kernel(
    bf16* __restrict__ X, const float* __restrict__ s, const float* __restrict__ b)
{
  __shared__ float part[4];
  int t = blockIdx.x, d = threadIdx.x;
  int n = t % NSEQ;
  int lane = threadIdx.x & 63, w = threadIdx.x >> 6;
  float x = cvt(X[(size_t)t*DMODEL + d]);
  float v = x;
  #pragma unroll
  for (int off = 32; off; off >>= 1) v += __shfl_xor(v, off, 64);
  if (lane == 0) part[w] = v;
  __syncthreads();
  float mean = (part[0]+part[1]+part[2]+part[3]) * (1.f/256.f);
  float diff = x - mean;
  float vv = diff*diff;
  #pragma unroll
  for (int off = 32; off; off >>= 1) vv += __shfl_xor(vv, off, 64);
  __syncthreads();
  if (lane == 0) part[w] = vv;
  __syncthreads();
  float var = (part[0]+part[1]+part[2]+part[3]) * (1.f/256.f);
  float y = diff * rsqrtf(var + 1e-6f) * s[d] + b[d];
  float e = (float)(2*(d>>1)) / 256.f;
  float ang = (float)n * powf(10000.f, -e);
  y += (d & 1) ? cosf(ang) : sinf(ang);
  X[(size_t)t*DMODEL + d] = __float2bfloat16(y);
}

// ---- tiled GEMM, 128x128 tile, BK=16, 256 thr, 8x8 microtile --------------
// MODE 0: plain A    MODE 1: LN-fused A loader
// A row   = aOff + rollmap(m0+m)  (roll within each 192-seq, rollShift)
// C row   = cOff + m0 + m
template<int MODE, bool ADD, bool GELU, typename AT>
__global__ __launch_bounds__(256) void gemm(
    const AT* __restrict__ A, int lda, int aOff,
    const float* __restrict__ mu, const float* __restrict__ rs,
    const float* __restrict__ lnS, const float* __restrict__ lnB,
    const float* __restrict__ W, int ldw, const float* __restrict__ bias,
    bf16* __restrict__ C, int ldc, int cOff, int K, int rollShift)
{
  __shared__ float As[16][132];
  __shared__ float Bs[16][132];
  const int tid = threadIdx.x;
  const int tx = tid & 15, ty = tid >> 4;
  const int m0 = blockIdx.y * 128, n0 = blockIdx.x * 128;
  float acc[8][8] = {};

  for (int k0 = 0; k0 < K; k0 += 16){
    #pragma unroll
    for (int i = 0; i < 8; i++){
      int idx = i*256 + tid;
      int m = idx >> 4, k = idx & 15;
      int gk = k0 + k;
      float v = 0.f;
      if (gk < K){
        int gm = m0 + m;
        int row = gm;
        if (rollShift){
          int bb = gm / NSEQ;
          int n  = gm - bb*NSEQ;
          n += rollShift; if (n >= NSEQ) n -= NSEQ;
          row = bb*NSEQ + n;
        }
        size_t arow = (size_t)aOff + row;
        if (MODE == 0) v = cvt(A[arow * lda + gk]);
        else v = (cvt(A[arow * lda + gk]) - mu[arow]) * rs[arow]
                 * lnS[gk] + lnB[gk];
      }
      As[k][m] = v;
    }
    #pragma unroll
    for (int i = 0; i < 8; i++){
      int idx = i*256 + tid;
      int k = idx >> 7, n = idx & 127;
      int gk = k0 + k;
      Bs[k][n] = (gk < K) ? W[(size_t)gk * ldw + (n0 + n)] : 0.f;
    }
    __syncthreads();
    #pragma unroll
    for (int kk = 0; kk < 16; kk++){
      const float4 a0 = *reinterpret_cast<const float4*>(&As[kk][ty*8]);
      const float4 a1 = *reinterpret_cast<const float4*>(&As[kk][ty*8+4]);
      const float4 b0 = *reinterpret_cast<const float4*>(&Bs[kk][tx*8]);
      const float4 b1 = *reinterpret_cast<const float4*>(&Bs[kk][tx*8+4]);
      const float a[8] = {a0.x,a0.y,a0.z,a0.w,a1.x,a1.y,a1.z,a1.w};
      const float b[8] = {b0.x,b0.y,b0.z,b0.w,b1.x,b1.y,b1.z,b1.w};
      #pragma unroll
      for (int i = 0; i < 8; i++)
        #pragma unroll
        for (int j = 0; j < 8; j++)
          acc[i][j] += a[i] * b[j];
    }
    __syncthreads();
  }

  #pragma unroll
  for (int i = 0; i < 8; i++){
    size_t m = (size_t)cOff + m0 + ty*8 + i;
    #pragma unroll
    for (int j = 0; j < 8; j++){
      int n = n0 + tx*8 + j;
      float r = acc[i][j] + bias[n];
      if (ADD) r += cvt(C[m * ldc + n]);
      if (GELU) r = gelu_f(r);
      C[m * ldc + n] = __float2bfloat16(r);
    }
  }
}

// ---- full-row GEMM (BM=64, BN=CPT*32) -------------------------------------
// MODE 2: concat(pts[row,0:K1] (f32), Xr[row,0:256] (bf16)) @ W  (skip layer)
// MODE 3: concat(Ft[row,0:256] (bf16), views[row/192,0:27] (f32)) @ W (rgb1)
template<int MODE, bool GELU, int CPT, typename T1, typename T2>
__global__ __launch_bounds__(256) void gemm_rowblk(
    const T1* __restrict__ A, const T2* __restrict__ A2,
    const float* __restrict__ W, const float* __restrict__ bias,
    bf16* __restrict__ C, int K, int K1)
{
  const int Nc = CPT*32;
  __shared__ float As[16][68];
  __shared__ float Bs[16][CPT*32];
  const int tid = threadIdx.x;
  const int tx = tid & 31, ty = tid >> 5;
  const size_t m0 = (size_t)blockIdx.x * 64;
  float acc[8][CPT] = {};

  for (int k0 = 0; k0 < K; k0 += 16){
    #pragma unroll
    for (int i = 0; i < 4; i++){
      int idx = i*256 + tid;
      int m = idx >> 4, kk = idx & 15;
      int gk = k0 + kk;
      float vv = 0.f;
      if (gk < K){
        size_t row = m0 + m;
        if (MODE == 2) vv = (gk < K1) ? cvt(A[row*K1 + gk]) : cvt(A2[row*256 + (gk-K1)]);
        else           vv = (gk < K1) ? cvt(A[row*256 + gk]) : cvt(A2[(row/NSEQ)*27 + (gk-K1)]);
      }
      As[kk][m] = vv;
    }
    #pragma unroll
    for (int i = 0; i < CPT*2; i++){
      int idx = i*256 + tid;
      int kk = idx / Nc, n = idx % Nc;
      int gk = k0 + kk;
      Bs[kk][n] = (gk < K) ? W[(size_t)gk*Nc + n] : 0.f;
    }
    __syncthreads();
    #pragma unroll
    for (int kk = 0; kk < 16; kk++){
      float a[8];
      #pragma unroll
      for (int i = 0; i < 8; i++) a[i] = As[kk][ty*8 + i];
      float b[CPT];
      #pragma unroll
      for (int j = 0; j < CPT; j++) b[j] = Bs[kk][tx*CPT + j];
      #pragma unroll
      for (int i = 0; i < 8; i++)
        #pragma unroll
        for (int j = 0; j < CPT; j++)
          acc[i][j] += a[i] * b[j];
    }
    __syncthreads();
  }
  #pragma unroll
  for (int i = 0; i < 8; i++){
    size_t m = m0 + ty*8 + i;
    #pragma unroll
    for (int j = 0; j < CPT; j++){
      int n = tx*CPT + j;
      float r = acc[i][j] + bias[n];
      if (GELU) r = gelu_f(r);
      C[m*256 + n] = __float2bfloat16(r);
    }
  }
}

// ---- lightweight windowed attention: softmax(QK^T/sqrt(hd)) @ V -----------
// One 8-token window per block. Q,K,V precomputed bf16 [chunkM,256].
// O overwrites Q (block-local rows). LDS rows padded to 257 (bank-conflict-free).
__global__ __launch_bounds__(256) void attn_lite(
    bf16* __restrict__ Qg, const bf16* __restrict__ Kg, const bf16* __restrict__ Vg)
{
  __shared__ float qs[8][257], ks[8][257], vs[8][257];
  __shared__ float sc[8][8][8];   // [h][q][k]
  const int c = threadIdx.x;
  const size_t base = (size_t)blockIdx.x * 8 * 256;
  #pragma unroll
  for (int j = 0; j < 8; j++){
    qs[j][c] = cvt(Qg[base + j*256 + c]);
    ks[j][c] = cvt(Kg[base + j*256 + c]);
    vs[j][c] = cvt(Vg[base + j*256 + c]);
  }
  __syncthreads();

  const float scale = 0.17677669529663687f; // 1/sqrt(32)
  #pragma unroll
  for (int r = 0; r < 2; r++){
    int idx = r*256 + c;
    int h = idx >> 6, qi = (idx >> 3) & 7, ki = idx & 7;
    float s = 0.f;
    #pragma unroll
    for (int d = 0; d < 32; d++) s += qs[qi][h*32+d] * ks[ki][h*32+d];
    sc[h][qi][ki] = s * scale;
  }
  __syncthreads();

  if (c < 64){
    int h = c >> 3, qi = c & 7;
    float mx = -1e30f;
    #pragma unroll
    for (int u = 0; u < 8; u++) mx = fmaxf(mx, sc[h][qi][u]);
    float e[8], sum = 0.f;
    #pragma unroll
    for (int u = 0; u < 8; u++){ e[u] = __expf(sc[h][qi][u] - mx); sum += e[u]; }
    float inv = 1.f / sum;
    #pragma unroll
    for (int u = 0; u < 8; u++) sc[h][qi][u] = e[u] * inv;
  }
  __syncthreads();

  {
    int h = c >> 5;
    #pragma unroll
    for (int j = 0; j < 8; j++){
      float o = 0.f;
      #pragma unroll
      for (int u = 0; u < 8; u++) o += sc[h][j][u] * vs[u][c];
      Qg[base + j*256 + c] = __float2bfloat16(o);
    }
  }
}

// ---- alpha head with fused ln_f: one wave per token (f32 out) -------------
__global__ __launch_bounds__(256) void alpha_kernel(
    const bf16* __restrict__ X, const float* __restrict__ mu,
    const float* __restrict__ rs, const float* __restrict__ s,
    const float* __restrict__ b, const float* __restrict__ wa,
    const float* __restrict__ ba, float* __restrict__ out)
{
  int lane = threadIdx.x & 63, w = threadIdx.x >> 6;
  size_t t = (size_t)blockIdx.x * 4 + w;
  float m = mu[t], r = rs[t];
  float acc = 0.f;
  #pragma unroll
  for (int j = 0; j < 4; j++){
    int c = lane + 64*j;
    float y = (cvt(X[t*DMODEL + c]) - m) * r * s[c] + b[c];
    acc += y * wa[c];
  }
  #pragma unroll
  for (int off = 32; off; off >>= 1) acc += __shfl_down(acc, off, 64);
  if (lane == 0) out[t] = acc + ba[0];
}

// ---- rgb2: t1 stored with ld=256 (cols 0..127), @ (128,3) + b (f32 out) ---
__global__ __launch_bounds__(256) void rgb2_kernel(
    const bf16* __restrict__ T1, const float* __restrict__ w2,
    const float* __restrict__ b2, float* __restrict__ out)
{
  int lane = threadIdx.x & 63, w = threadIdx.x >> 6;
  size_t t = (size_t)blockIdx.x * 4 + w;
  float h0 = cvt(T1[t*256 + lane]);
  float h1 = cvt(T1[t*256 + 64 + lane]);
  float a0 = h0*w2[lane*3+0] + h1*w2[(lane+64)*3+0];
  float a1 = h0*w2[lane*3+1] + h1*w2[(lane+64)*3+1];
  float a2 = h0*w2[lane*3+2] + h1*w2[(lane+64)*3+2];
  #pragma unroll
  for (int off = 32; off; off >>= 1){
    a0 += __shfl_down(a0, off, 64);
    a1 += __shfl_down(a1, off, 64);
    a2 += __shfl_down(a2, off, 64);
  }
  if (lane == 0){
    out[t*3+0] = a0 + b2[0];
    out[t*3+1] = a1 + b2[1];
    out[t*3+2] = a2 + b2[2];
  }
}

extern "C" void kernel_launch(void* const* d_in, const int* in_sizes, int n_in,
                              void* d_out, int out_size, void* d_ws, size_t ws_size,
                              hipStream_t stream)
{
  (void)in_sizes; (void)n_in; (void)out_size;
  const float* pts     = (const float*)d_in[0];
  const float* views   = (const float*)d_in[1];
  const float* w_in    = (const float*)d_in[2];
  const float* b_in    = (const float*)d_in[3];
  const float* ln_in_s = (const float*)d_in[4];
  const float* ln_in_b = (const float*)d_in[5];
  const float* ln1_s   = (const float*)d_in[6];
  const float* ln1_b   = (const float*)d_in[7];
  const float* wq      = (const float*)d_in[8];
  const float* bq      = (const float*)d_in[9];
  const float* wk      = (const float*)d_in[10];
  const float* bk      = (const float*)d_in[11];
  const float* wv      = (const float*)d_in[12];
  const float* bv      = (const float*)d_in[13];
  const float* wo      = (const float*)d_in[14];
  const float* bo      = (const float*)d_in[15];
  const float* ln2_s   = (const float*)d_in[16];
  const float* ln2_b   = (const float*)d_in[17];
  const float* w_mlp1  = (const float*)d_in[18];
  const float* b_mlp1  = (const float*)d_in[19];
  const float* w_mlp2  = (const float*)d_in[20];
  const float* b_mlp2  = (const float*)d_in[21];
  const float* w_skip  = (const float*)d_in[22];
  const float* b_skip  = (const float*)d_in[23];
  const float* ln_f_s  = (const float*)d_in[24];
  const float* ln_f_b  = (const float*)d_in[25];
  const float* w_alpha = (const float*)d_in[26];
  const float* b_alpha = (const float*)d_in[27];
  const float* w_feat  = (const float*)d_in[28];
  const float* b_feat  = (const float*)d_in[29];
  const float* w_rgb1  = (const float*)d_in[30];
  const float* b_rgb1  = (const float*)d_in[31];
  const float* w_rgb2  = (const float*)d_in[32];
  const float* b_rgb2  = (const float*)d_in[33];

  const size_t SZ = (size_t)T_TOK * DMODEL * 2;        // 100,663,296 B
  const size_t NEED = 2*SZ + (size_t)2*T_TOK*4;        // ~203 MB
  if (ws_size < NEED) return;

  char* wsp = (char*)d_ws;
  bf16* xr = (bf16*)(wsp);
  bf16* x2 = (bf16*)(wsp + SZ);
  float* mu = (float*)(wsp + 2*SZ);
  float* rs = mu + T_TOK;

  float* out_rgb   = (float*)d_out;
  float* out_alpha = out_rgb + (size_t)T_TOK * 3;

  dim3 blk(256);
  dim3 g256(2, T_TOK/128);       // full-T, Nc=256
  dim3 gC(2, CHUNKM/128);        // chunk, Nc=256
  dim3 gRow(T_TOK/64);
  dim3 gTok(T_TOK);
  dim3 gStat(T_TOK/4);
  dim3 gAttn(CHUNKM/8);

  const float* NF = nullptr;

  // x = pts @ w_in + b_in -> xr ; x = ln(x) + pe (in place)
  gemm<0,false,false,float><<<g256, blk, 0, stream>>>(pts, 63, 0, NF, NF, NF, NF,
      w_in, 256, b_in, xr, 256, 0, 63, 0);
  ln_pe_kernel<<<gTok, blk, 0, stream>>>(xr, ln_in_s, ln_in_b);

  for (int i = 0; i < 2; i++){
    const int shift = (i == 1) ? 4 : 0;
    const int shiftBack = (i == 1) ? (NSEQ - 4) : 0;
    const float* wq_i = wq + (size_t)i*65536;
    const float* wk_i = wk + (size_t)i*65536;
    const float* wv_i = wv + (size_t)i*65536;
    const float* wo_i = wo + (size_t)i*65536;
    const float* w1_i = w_mlp1 + (size_t)i*65536;
    const float* w2_i = w_mlp2 + (size_t)i*65536;
    const float* ws_i = w_skip + (size_t)i*81664; // 319*256

    // ln1 stats over full residual
    ln_stats_kernel<<<gStat, blk, 0, stream>>>(xr, mu, rs);

    // attention, chunked: Q/K/V buffers live inside x2 (3 x 24 MB)
    bf16* qb = x2;
    bf16* kb = x2 + (size_t)CHUNKM * 256;
    bf16* vb = x2 + (size_t)2 * CHUNKM * 256;
    for (int cch = 0; cch < CHUNKS; cch++){
      int base = cch * CHUNKM;
      // q,k,v = ln1(roll(x_chunk)) @ w + b   (LN + roll fused; rolled frame)
      gemm<1,false,false,bf16><<<gC, blk, 0, stream>>>(xr, 256, base, mu, rs,
          ln1_s + i*256, ln1_b + i*256, wq_i, 256, bq + i*256, qb, 256, 0, 256, shift);
      gemm<1,false,false,bf16><<<gC, blk, 0, stream>>>(xr, 256, base, mu, rs,
          ln1_s + i*256, ln1_b + i*256, wk_i, 256, bk + i*256, kb, 256, 0, 256, shift);
      gemm<1,false,false,bf16><<<gC, blk, 0, stream>>>(xr, 256, base, mu, rs,
          ln1_s + i*256, ln1_b + i*256, wv_i, 256, bv + i*256, vb, 256, 0, 256, shift);
      // softmax + PV per window; O overwrites qb
      attn_lite<<<gAttn, blk, 0, stream>>>(qb, kb, vb);
      // x_chunk += roll_back(O) @ wo + bo
      gemm<0,true,false,bf16><<<gC, blk, 0, stream>>>(qb, 256, 0, NF, NF, NF, NF,
          wo_i, 256, bo + i*256, xr, 256, base, 256, shiftBack);
    }

    // mlp (ln2 stats over updated residual)
    ln_stats_kernel<<<gStat, blk, 0, stream>>>(xr, mu, rs);
    gemm<1,false,true ,bf16><<<g256, blk, 0, stream>>>(xr, 256, 0, mu, rs,
        ln2_s + i*256, ln2_b + i*256, w1_i, 256, b_mlp1 + i*256, x2, 256, 0, 256, 0);
    gemm<0,true ,false,bf16><<<g256, blk, 0, stream>>>(x2, 256, 0, NF, NF, NF, NF,
        w2_i, 256, b_mlp2 + i*256, xr, 256, 0, 256, 0);
    // x = gelu(concat(pts, x) @ w_skip + b_skip) -> x2, then swap
    gemm_rowblk<2,true,8,float,bf16><<<gRow, blk, 0, stream>>>(pts, xr, ws_i,
        b_skip + i*256, x2, 319, 63);
    bf16* tmp = xr; xr = x2; x2 = tmp;
  }

  // head
  ln_stats_kernel<<<gStat, blk, 0, stream>>>(xr, mu, rs);
  alpha_kernel<<<gStat, blk, 0, stream>>>(xr, mu, rs, ln_f_s, ln_f_b,
      w_alpha, b_alpha, out_alpha);
  // feature = ln_f(x) @ w_feat + b_feat -> x2
  gemm<1,false,false,bf16><<<g256, blk, 0, stream>>>(xr, 256, 0, mu, rs,
      ln_f_s, ln_f_b, w_feat, 256, b_feat, x2, 256, 0, 256, 0);
  // t1 = gelu(concat(feature, views) @ w_rgb1 + b_rgb1) -> xr cols 0..127
  gemm_rowblk<3,true,4,bf16,float><<<gRow, blk, 0, stream>>>(x2, views, w_rgb1,
      b_rgb1, xr, 283, 256);
  rgb2_kernel<<<gStat, blk, 0, stream>>>(xr, w_rgb2, b_rgb2, out_rgb);
}

// Round 9
// 5908.726 us; speedup vs baseline: 3.1697x; 2.1394x over previous
//
#include <hip/hip_runtime.h>
#include <hip/hip_bf16.h>
#include <math.h>

typedef __hip_bfloat16 bf16;
typedef __attribute__((ext_vector_type(8))) short short8;
typedef __attribute__((ext_vector_type(4))) float f32x4;

#define T_TOK 196608   // B*N = 1024*192
#define NSEQ  192
#define DMODEL 256
#define CHUNKS 4
#define CHUNKM (T_TOK/CHUNKS)   // 49152 tokens = 256 sequences

__device__ __forceinline__ float cvt(float v){ return v; }
__device__ __forceinline__ float cvt(bf16 v){ return __bfloat162float(v); }
__device__ __forceinline__ short bfbits(float f){
  bf16 h = __float2bfloat16(f); return *reinterpret_cast<short*>(&h);
}

__device__ __forceinline__ float gelu_f(float x){
  const float k0 = 0.7978845608028654f; // sqrt(2/pi)
  return 0.5f*x*(1.0f + tanhf(k0*(x + 0.044715f*x*x*x)));
}

// ---- weight convert+transpose: WT[n][k] = bf16(W[k][n]), zero-pad k>=K ----
__global__ __launch_bounds__(256) void w2b_kernel(
    const float* __restrict__ src, bf16* __restrict__ dst, int K, int N, int Kpad)
{
  int idx = blockIdx.x*256 + threadIdx.x;
  if (idx >= N*Kpad) return;
  int n = idx / Kpad, k = idx - n*Kpad;
  dst[idx] = __float2bfloat16(k < K ? src[(size_t)k*N + n] : 0.f);
}

// ---- per-token LN stats (wave per token, 4 tokens/block) ------------------
__global__ __launch_bounds__(256) void ln_stats_kernel(
    const bf16* __restrict__ X, float* __restrict__ mu, float* __restrict__ rsd)
{
  int lane = threadIdx.x & 63, w = threadIdx.x >> 6;
  size_t t = (size_t)blockIdx.x * 4 + w;
  float x[4];
  #pragma unroll
  for (int j = 0; j < 4; j++) x[j] = cvt(X[t*DMODEL + lane + 64*j]);
  float s = x[0] + x[1] + x[2] + x[3];
  #pragma unroll
  for (int off = 32; off; off >>= 1) s += __shfl_xor(s, off, 64);
  float m = s * (1.f/256.f);
  float q = 0.f;
  #pragma unroll
  for (int j = 0; j < 4; j++){ float d = x[j] - m; q += d*d; }
  #pragma unroll
  for (int off = 32; off; off >>= 1) q += __shfl_xor(q, off, 64);
  if (lane == 0){ mu[t] = m; rsd[t] = rsqrtf(q*(1.f/256.f) + 1e-6f); }
}

// ---- in-place: x = ln(x)*s+b + pos_embed  (block per token) ---------------
__global__ __launch_bounds__(256) void ln_pe_kernel(
    bf16* __restrict__ X, const float* __restrict__ s, const float* __restrict__ b)
{
  __shared__ float part[4];
  int t = blockIdx.x, d = threadIdx.x;
  int n = t % NSEQ;
  int lane = threadIdx.x & 63, w = threadIdx.x >> 6;
  float x = cvt(X[(size_t)t*DMODEL + d]);
  float v = x;
  #pragma unroll
  for (int off = 32; off; off >>= 1) v += __shfl_xor(v, off, 64);
  if (lane == 0) part[w] = v;
  __syncthreads();
  float mean = (part[0]+part[1]+part[2]+part[3]) * (1.f/256.f);
  float diff = x - mean;
  float vv = diff*diff;
  #pragma unroll
  for (int off = 32; off; off >>= 1) vv += __shfl_xor(vv, off, 64);
  __syncthreads();
  if (lane == 0) part[w] = vv;
  __syncthreads();
  float var = (part[0]+part[1]+part[2]+part[3]) * (1.f/256.f);
  float y = diff * rsqrtf(var + 1e-6f) * s[d] + b[d];
  float e = (float)(2*(d>>1)) / 256.f;
  float ang = (float)n * powf(10000.f, -e);
  y += (d & 1) ? cosf(ang) : sinf(ang);
  X[(size_t)t*DMODEL + d] = __float2bfloat16(y);
}

// ---- MFMA GEMM: C[M,Nc] = A[M,K] @ W[K,Nc], 128x128 tile, 4 waves ---------
// Each wave: 64x64 via 4x4 mfma_f32_16x16x32_bf16. B read from WT[N][Kpad]
// (global, L2-resident). A staged in LDS (pad 40) with fused transforms:
// MODE 0: plain bf16 A     MODE 4: plain f32 A
// MODE 1: LN((Ab-mu)*rs)*lnS+lnB  (bf16 A)
// MODE 2: concat(Af[row,0:K1], Ab[row,0:256])       (skip layer)
// MODE 3: concat(Ab[row,0:256], Af[row/192,0:27])   (rgb1)
// rollShift (MODE<=1): A row n -> (n+rollShift)%192 within each sequence.
template<int MODE, bool ADD, bool GELU>
__global__ __launch_bounds__(256) void gemm_mfma(
    const float* __restrict__ Af, const bf16* __restrict__ Ab, int lda, int aOff,
    const float* __restrict__ mu, const float* __restrict__ rs,
    const float* __restrict__ lnS, const float* __restrict__ lnB,
    const bf16* __restrict__ WT, int Kpad, const float* __restrict__ bias,
    bf16* __restrict__ C, int ldc, int cOff, int K, int K1, int rollShift)
{
  __shared__ short As[128*40];   // [m][k] bf16 bits, row padded to 40
  const int tid = threadIdx.x;
  const int lane = tid & 63, wid = tid >> 6;
  const int wm = wid >> 1, wn = wid & 1;
  const int col16 = lane & 15, quad = lane >> 4;
  const int m0 = blockIdx.y * 128, n0 = blockIdx.x * 128;
  const int sm = tid >> 1, half = tid & 1;   // staging: row, k-half

  f32x4 acc[4][4];
  #pragma unroll
  for (int i = 0; i < 4; i++)
    #pragma unroll
    for (int j = 0; j < 4; j++) acc[i][j] = (f32x4){0.f,0.f,0.f,0.f};

  // precompute staging source row
  int row = m0 + sm;
  if ((MODE == 0 || MODE == 1) && rollShift){
    int bb = row / NSEQ;
    int n  = row - bb*NSEQ;
    n += rollShift; if (n >= NSEQ) n -= NSEQ;
    row = bb*NSEQ + n;
  }
  const size_t arow = (size_t)aOff + row;
  float lnMu = 0.f, lnRs = 0.f;
  if (MODE == 1){ lnMu = mu[arow]; lnRs = rs[arow]; }

  for (int k0 = 0; k0 < Kpad; k0 += 32){
    // ---- stage A tile (128 x 32): thread covers (sm, half*16 + 0..15) ----
    short tmp[16] __attribute__((aligned(16)));
    #pragma unroll
    for (int j = 0; j < 16; j++){
      int gk = k0 + half*16 + j;
      float v = 0.f;
      if (gk < K){
        if (MODE == 0)      v = cvt(Ab[arow*lda + gk]);
        else if (MODE == 4) v = Af[arow*lda + gk];
        else if (MODE == 1) v = (cvt(Ab[arow*lda + gk]) - lnMu) * lnRs
                                * lnS[gk] + lnB[gk];
        else if (MODE == 2) v = (gk < K1) ? Af[arow*K1 + gk]
                                          : cvt(Ab[arow*256 + (gk-K1)]);
        else                v = (gk < K1) ? cvt(Ab[arow*256 + gk])
                                          : Af[(arow/NSEQ)*27 + (gk-K1)];
      }
      tmp[j] = bfbits(v);
    }
    *(short8*)&As[sm*40 + half*16]     = *(short8*)&tmp[0];
    *(short8*)&As[sm*40 + half*16 + 8] = *(short8*)&tmp[8];
    __syncthreads();

    // ---- fragments + 16 MFMA ----
    short8 afr[4];
    #pragma unroll
    for (int mi = 0; mi < 4; mi++)
      afr[mi] = *(const short8*)&As[(wm*64 + mi*16 + col16)*40 + quad*8];
    short8 bfr[4];
    #pragma unroll
    for (int ni = 0; ni < 4; ni++)
      bfr[ni] = *(const short8*)((const short*)WT
                 + (size_t)(n0 + wn*64 + ni*16 + col16)*Kpad + k0 + quad*8);
    #pragma unroll
    for (int mi = 0; mi < 4; mi++)
      #pragma unroll
      for (int ni = 0; ni < 4; ni++)
        acc[mi][ni] = __builtin_amdgcn_mfma_f32_16x16x32_bf16(
            afr[mi], bfr[ni], acc[mi][ni], 0, 0, 0);
    __syncthreads();
  }

  // ---- epilogue: C row = quad*4+r, col = lane&15 per 16x16 tile ----
  #pragma unroll
  for (int ni = 0; ni < 4; ni++){
    int ncol = n0 + wn*64 + ni*16 + col16;
    float bv = bias[ncol];
    #pragma unroll
    for (int mi = 0; mi < 4; mi++){
      f32x4 a = acc[mi][ni];
      #pragma unroll
      for (int r = 0; r < 4; r++){
        size_t mrow = (size_t)cOff + m0 + wm*64 + mi*16 + quad*4 + r;
        float val = a[r] + bv;
        if (ADD) val += cvt(C[mrow*ldc + ncol]);
        if (GELU) val = gelu_f(val);
        C[mrow*ldc + ncol] = __float2bfloat16(val);
      }
    }
  }
}

// ---- lightweight windowed attention: softmax(QK^T/sqrt(hd)) @ V -----------
__global__ __launch_bounds__(256) void attn_lite(
    bf16* __restrict__ Qg, const bf16* __restrict__ Kg, const bf16* __restrict__ Vg)
{
  __shared__ float qs[8][257], ks[8][257], vs[8][257];
  __shared__ float sc[8][8][8];   // [h][q][k]
  const int c = threadIdx.x;
  const size_t base = (size_t)blockIdx.x * 8 * 256;
  #pragma unroll
  for (int j = 0; j < 8; j++){
    qs[j][c] = cvt(Qg[base + j*256 + c]);
    ks[j][c] = cvt(Kg[base + j*256 + c]);
    vs[j][c] = cvt(Vg[base + j*256 + c]);
  }
  __syncthreads();

  const float scale = 0.17677669529663687f; // 1/sqrt(32)
  #pragma unroll
  for (int r = 0; r < 2; r++){
    int idx = r*256 + c;
    int h = idx >> 6, qi = (idx >> 3) & 7, ki = idx & 7;
    float s = 0.f;
    #pragma unroll
    for (int d = 0; d < 32; d++) s += qs[qi][h*32+d] * ks[ki][h*32+d];
    sc[h][qi][ki] = s * scale;
  }
  __syncthreads();

  if (c < 64){
    int h = c >> 3, qi = c & 7;
    float mx = -1e30f;
    #pragma unroll
    for (int u = 0; u < 8; u++) mx = fmaxf(mx, sc[h][qi][u]);
    float e[8], sum = 0.f;
    #pragma unroll
    for (int u = 0; u < 8; u++){ e[u] = __expf(sc[h][qi][u] - mx); sum += e[u]; }
    float inv = 1.f / sum;
    #pragma unroll
    for (int u = 0; u < 8; u++) sc[h][qi][u] = e[u] * inv;
  }
  __syncthreads();

  {
    int h = c >> 5;
    #pragma unroll
    for (int j = 0; j < 8; j++){
      float o = 0.f;
      #pragma unroll
      for (int u = 0; u < 8; u++) o += sc[h][j][u] * vs[u][c];
      Qg[base + j*256 + c] = __float2bfloat16(o);
    }
  }
}

// ---- alpha head with fused ln_f: one wave per token (f32 out) -------------
__global__ __launch_bounds__(256) void alpha_kernel(
    const bf16* __restrict__ X, const float* __restrict__ mu,
    const float* __restrict__ rs, const float* __restrict__ s,
    const float* __restrict__ b, const float* __restrict__ wa,
    const float* __restrict__ ba, float* __restrict__ out)
{
  int lane = threadIdx.x & 63, w = threadIdx.x >> 6;
  size_t t = (size_t)blockIdx.x * 4 + w;
  float m = mu[t], r = rs[t];
  float acc = 0.f;
  #pragma unroll
  for (int j = 0; j < 4; j++){
    int c = lane + 64*j;
    float y = (cvt(X[t*DMODEL + c]) - m) * r * s[c] + b[c];
    acc += y * wa[c];
  }
  #pragma unroll
  for (int off = 32; off; off >>= 1) acc += __shfl_down(acc, off, 64);
  if (lane == 0) out[t] = acc + ba[0];
}

// ---- rgb2: t1 stored with ld=256 (cols 0..127), @ (128,3) + b (f32 out) ---
__global__ __launch_bounds__(256) void rgb2_kernel(
    const bf16* __restrict__ T1, const float* __restrict__ w2,
    const float* __restrict__ b2, float* __restrict__ out)
{
  int lane = threadIdx.x & 63, w = threadIdx.x >> 6;
  size_t t = (size_t)blockIdx.x * 4 + w;
  float h0 = cvt(T1[t*256 + lane]);
  float h1 = cvt(T1[t*256 + 64 + lane]);
  float a0 = h0*w2[lane*3+0] + h1*w2[(lane+64)*3+0];
  float a1 = h0*w2[lane*3+1] + h1*w2[(lane+64)*3+1];
  float a2 = h0*w2[lane*3+2] + h1*w2[(lane+64)*3+2];
  #pragma unroll
  for (int off = 32; off; off >>= 1){
    a0 += __shfl_down(a0, off, 64);
    a1 += __shfl_down(a1, off, 64);
    a2 += __shfl_down(a2, off, 64);
  }
  if (lane == 0){
    out[t*3+0] = a0 + b2[0];
    out[t*3+1] = a1 + b2[1];
    out[t*3+2] = a2 + b2[2];
  }
}

extern "C" void kernel_launch(void* const* d_in, const int* in_sizes, int n_in,
                              void* d_out, int out_size, void* d_ws, size_t ws_size,
                              hipStream_t stream)
{
  (void)in_sizes; (void)n_in; (void)out_size;
  const float* pts     = (const float*)d_in[0];
  const float* views   = (const float*)d_in[1];
  const float* w_in    = (const float*)d_in[2];
  const float* b_in    = (const float*)d_in[3];
  const float* ln_in_s = (const float*)d_in[4];
  const float* ln_in_b = (const float*)d_in[5];
  const float* ln1_s   = (const float*)d_in[6];
  const float* ln1_b   = (const float*)d_in[7];
  const float* wq      = (const float*)d_in[8];
  const float* bq      = (const float*)d_in[9];
  const float* wk      = (const float*)d_in[10];
  const float* bk      = (const float*)d_in[11];
  const float* wv      = (const float*)d_in[12];
  const float* bv      = (const float*)d_in[13];
  const float* wo      = (const float*)d_in[14];
  const float* bo      = (const float*)d_in[15];
  const float* ln2_s   = (const float*)d_in[16];
  const float* ln2_b   = (const float*)d_in[17];
  const float* w_mlp1  = (const float*)d_in[18];
  const float* b_mlp1  = (const float*)d_in[19];
  const float* w_mlp2  = (const float*)d_in[20];
  const float* b_mlp2  = (const float*)d_in[21];
  const float* w_skip  = (const float*)d_in[22];
  const float* b_skip  = (const float*)d_in[23];
  const float* ln_f_s  = (const float*)d_in[24];
  const float* ln_f_b  = (const float*)d_in[25];
  const float* w_alpha = (const float*)d_in[26];
  const float* b_alpha = (const float*)d_in[27];
  const float* w_feat  = (const float*)d_in[28];
  const float* b_feat  = (const float*)d_in[29];
  const float* w_rgb1  = (const float*)d_in[30];
  const float* b_rgb1  = (const float*)d_in[31];
  const float* w_rgb2  = (const float*)d_in[32];
  const float* b_rgb2  = (const float*)d_in[33];

  const size_t SZ = (size_t)T_TOK * DMODEL * 2;        // 100,663,296 B
  const size_t WT_ELEMS = 16384 + 2*(6*65536 + 81920) + 65536 + 36864;
  const size_t NEED = 2*SZ + (size_t)2*T_TOK*4 + WT_ELEMS*2;
  if (ws_size < NEED) return;

  char* wsp = (char*)d_ws;
  bf16* xr = (bf16*)(wsp);
  bf16* x2 = (bf16*)(wsp + SZ);
  float* mu = (float*)(wsp + 2*SZ);
  float* rs = mu + T_TOK;
  bf16* wtp = (bf16*)(wsp + 2*SZ + (size_t)2*T_TOK*4);

  // WT layout
  bf16* wt_in   = wtp;                       // 256 x 64
  bf16* wt_q[2], *wt_k[2], *wt_v[2], *wt_o[2], *wt_m1[2], *wt_m2[2], *wt_sk[2];
  bf16* p = wt_in + 16384;
  for (int i = 0; i < 2; i++){
    wt_q[i]  = p; p += 65536;
    wt_k[i]  = p; p += 65536;
    wt_v[i]  = p; p += 65536;
    wt_o[i]  = p; p += 65536;
    wt_m1[i] = p; p += 65536;
    wt_m2[i] = p; p += 65536;
    wt_sk[i] = p; p += 81920;                // 256 x 320
  }
  bf16* wt_feat = p; p += 65536;
  bf16* wt_rgb1 = p; p += 36864;             // 128 x 288

  float* out_rgb   = (float*)d_out;
  float* out_alpha = out_rgb + (size_t)T_TOK * 3;

  dim3 blk(256);
  dim3 g256(2, T_TOK/128);       // full-T, Nc=256
  dim3 gC(2, CHUNKM/128);        // chunk, Nc=256
  dim3 g128(1, T_TOK/128);       // full-T, Nc=128
  dim3 gTok(T_TOK);
  dim3 gStat(T_TOK/4);
  dim3 gAttn(CHUNKM/8);

  const float* NF = nullptr;
  const bf16*  NB = nullptr;

  // convert+transpose all weights to bf16 WT[N][Kpad]
  #define W2B(src, dst, K_, N_, KP_) \
    w2b_kernel<<<dim3(((N_)*(KP_)+255)/256), blk, 0, stream>>>(src, dst, K_, N_, KP_)
  W2B(w_in, wt_in, 63, 256, 64);
  for (int i = 0; i < 2; i++){
    W2B(wq + (size_t)i*65536, wt_q[i], 256, 256, 256);
    W2B(wk + (size_t)i*65536, wt_k[i], 256, 256, 256);
    W2B(wv + (size_t)i*65536, wt_v[i], 256, 256, 256);
    W2B(wo + (size_t)i*65536, wt_o[i], 256, 256, 256);
    W2B(w_mlp1 + (size_t)i*65536, wt_m1[i], 256, 256, 256);
    W2B(w_mlp2 + (size_t)i*65536, wt_m2[i], 256, 256, 256);
    W2B(w_skip + (size_t)i*81664, wt_sk[i], 319, 256, 320);
  }
  W2B(w_feat, wt_feat, 256, 256, 256);
  W2B(w_rgb1, wt_rgb1, 283, 128, 288);
  #undef W2B

  // x = pts @ w_in + b_in -> xr ; x = ln(x) + pe (in place)
  gemm_mfma<4,false,false><<<g256, blk, 0, stream>>>(pts, NB, 63, 0, NF, NF, NF, NF,
      wt_in, 64, b_in, xr, 256, 0, 63, 0, 0);
  ln_pe_kernel<<<gTok, blk, 0, stream>>>(xr, ln_in_s, ln_in_b);

  for (int i = 0; i < 2; i++){
    const int shift = (i == 1) ? 4 : 0;
    const int shiftBack = (i == 1) ? (NSEQ - 4) : 0;

    // ln1 stats over full residual
    ln_stats_kernel<<<gStat, blk, 0, stream>>>(xr, mu, rs);

    // attention, chunked: Q/K/V buffers live inside x2 (3 x 24 MB)
    bf16* qb = x2;
    bf16* kb = x2 + (size_t)CHUNKM * 256;
    bf16* vb = x2 + (size_t)2 * CHUNKM * 256;
    for (int cch = 0; cch < CHUNKS; cch++){
      int base = cch * CHUNKM;
      gemm_mfma<1,false,false><<<gC, blk, 0, stream>>>(NF, xr, 256, base, mu, rs,
          ln1_s + i*256, ln1_b + i*256, wt_q[i], 256, bq + i*256,
          qb, 256, 0, 256, 0, shift);
      gemm_mfma<1,false,false><<<gC, blk, 0, stream>>>(NF, xr, 256, base, mu, rs,
          ln1_s + i*256, ln1_b + i*256, wt_k[i], 256, bk + i*256,
          kb, 256, 0, 256, 0, shift);
      gemm_mfma<1,false,false><<<gC, blk, 0, stream>>>(NF, xr, 256, base, mu, rs,
          ln1_s + i*256, ln1_b + i*256, wt_v[i], 256, bv + i*256,
          vb, 256, 0, 256, 0, shift);
      attn_lite<<<gAttn, blk, 0, stream>>>(qb, kb, vb);
      // x_chunk += roll_back(O) @ wo + bo
      gemm_mfma<0,true,false><<<gC, blk, 0, stream>>>(NF, qb, 256, 0, NF, NF, NF, NF,
          wt_o[i], 256, bo + i*256, xr, 256, base, 256, 0, shiftBack);
    }

    // mlp
    ln_stats_kernel<<<gStat, blk, 0, stream>>>(xr, mu, rs);
    gemm_mfma<1,false,true ><<<g256, blk, 0, stream>>>(NF, xr, 256, 0, mu, rs,
        ln2_s + i*256, ln2_b + i*256, wt_m1[i], 256, b_mlp1 + i*256,
        x2, 256, 0, 256, 0, 0);
    gemm_mfma<0,true ,false><<<g256, blk, 0, stream>>>(NF, x2, 256, 0, NF, NF, NF, NF,
        wt_m2[i], 256, b_mlp2 + i*256, xr, 256, 0, 256, 0, 0);
    // x = gelu(concat(pts, x) @ w_skip + b_skip) -> x2, then swap
    gemm_mfma<2,false,true ><<<g256, blk, 0, stream>>>(pts, xr, 0, 0, NF, NF, NF, NF,
        wt_sk[i], 320, b_skip + i*256, x2, 256, 0, 319, 63, 0);
    bf16* tmp = xr; xr = x2; x2 = tmp;
  }

  // head
  ln_stats_kernel<<<gStat, blk, 0, stream>>>(xr, mu, rs);
  alpha_kernel<<<gStat, blk, 0, stream>>>(xr, mu, rs, ln_f_s, ln_f_b,
      w_alpha, b_alpha, out_alpha);
  // feature = ln_f(x) @ w_feat + b_feat -> x2
  gemm_mfma<1,false,false><<<g256, blk, 0, stream>>>(NF, xr, 256, 0, mu, rs,
      ln_f_s, ln_f_b, wt_feat, 256, b_feat, x2, 256, 0, 256, 0, 0);
  // t1 = gelu(concat(feature, views) @ w_rgb1 + b_rgb1) -> xr cols 0..127
  gemm_mfma<3,false,true ><<<g128, blk, 0, stream>>>(views, x2, 0, 0, NF, NF, NF, NF,
      wt_rgb1, 288, b_rgb1, xr, 256, 0, 283, 256, 0);
  rgb2_kernel<<<gStat, blk, 0, stream>>>(xr, w_rgb2, b_rgb2, out_rgb);
}

// Round 10
// 2991.797 us; speedup vs baseline: 6.2601x; 1.9750x over previous
//
#include <hip/hip_runtime.h>
#include <hip/hip_bf16.h>
#include <math.h>

typedef __hip_bfloat16 bf16;
typedef __attribute__((ext_vector_type(8))) short short8;
typedef __attribute__((ext_vector_type(4))) float f32x4;

#define T_TOK 196608   // B*N = 1024*192
#define NSEQ  192
#define DMODEL 256
#define CHUNKS 4
#define CHUNKM (T_TOK/CHUNKS)   // 49152 tokens = 256 sequences

__device__ __forceinline__ float cvt(float v){ return v; }
__device__ __forceinline__ float cvt(bf16 v){ return __bfloat162float(v); }
__device__ __forceinline__ short bfbits(float f){
  bf16 h = __float2bfloat16(f); return *reinterpret_cast<short*>(&h);
}
__device__ __forceinline__ float blo(unsigned u){ return __uint_as_float(u << 16); }
__device__ __forceinline__ float bhi(unsigned u){ return __uint_as_float(u & 0xffff0000u); }
__device__ __forceinline__ unsigned pack2(float a, float b){
  return ((unsigned)(unsigned short)bfbits(a)) | (((unsigned)(unsigned short)bfbits(b)) << 16);
}

__device__ __forceinline__ float gelu_f(float x){
  const float k0 = 0.7978845608028654f; // sqrt(2/pi)
  return 0.5f*x*(1.0f + tanhf(k0*(x + 0.044715f*x*x*x)));
}

// ---- weight convert+transpose: WT[n][k] = bf16(W[k][n]), zero-pad k>=K ----
__global__ __launch_bounds__(256) void w2b_kernel(
    const float* __restrict__ src, bf16* __restrict__ dst, int K, int N, int Kpad)
{
  int idx = blockIdx.x*256 + threadIdx.x;
  if (idx >= N*Kpad) return;
  int n = idx / Kpad, k = idx - n*Kpad;
  dst[idx] = __float2bfloat16(k < K ? src[(size_t)k*N + n] : 0.f);
}

// ---- per-token LN stats (wave per token, 4 tokens/block) ------------------
__global__ __launch_bounds__(256) void ln_stats_kernel(
    const bf16* __restrict__ X, float* __restrict__ mu, float* __restrict__ rsd)
{
  int lane = threadIdx.x & 63, w = threadIdx.x >> 6;
  size_t t = (size_t)blockIdx.x * 4 + w;
  float x[4];
  #pragma unroll
  for (int j = 0; j < 4; j++) x[j] = cvt(X[t*DMODEL + lane + 64*j]);
  float s = x[0] + x[1] + x[2] + x[3];
  #pragma unroll
  for (int off = 32; off; off >>= 1) s += __shfl_xor(s, off, 64);
  float m = s * (1.f/256.f);
  float q = 0.f;
  #pragma unroll
  for (int j = 0; j < 4; j++){ float d = x[j] - m; q += d*d; }
  #pragma unroll
  for (int off = 32; off; off >>= 1) q += __shfl_xor(q, off, 64);
  if (lane == 0){ mu[t] = m; rsd[t] = rsqrtf(q*(1.f/256.f) + 1e-6f); }
}

// ---- in-place: x = ln(x)*s+b + pos_embed  (block per token) ---------------
__global__ __launch_bounds__(256) void ln_pe_kernel(
    bf16* __restrict__ X, const float* __restrict__ s, const float* __restrict__ b)
{
  __shared__ float part[4];
  int t = blockIdx.x, d = threadIdx.x;
  int n = t % NSEQ;
  int lane = threadIdx.x & 63, w = threadIdx.x >> 6;
  float x = cvt(X[(size_t)t*DMODEL + d]);
  float v = x;
  #pragma unroll
  for (int off = 32; off; off >>= 1) v += __shfl_xor(v, off, 64);
  if (lane == 0) part[w] = v;
  __syncthreads();
  float mean = (part[0]+part[1]+part[2]+part[3]) * (1.f/256.f);
  float diff = x - mean;
  float vv = diff*diff;
  #pragma unroll
  for (int off = 32; off; off >>= 1) vv += __shfl_xor(vv, off, 64);
  __syncthreads();
  if (lane == 0) part[w] = vv;
  __syncthreads();
  float var = (part[0]+part[1]+part[2]+part[3]) * (1.f/256.f);
  float y = diff * rsqrtf(var + 1e-6f) * s[d] + b[d];
  float e = (float)(2*(d>>1)) / 256.f;
  float ang = (float)n * powf(10000.f, -e);
  y += (d & 1) ? cosf(ang) : sinf(ang);
  X[(size_t)t*DMODEL + d] = __float2bfloat16(y);
}

// ---- MFMA GEMM: C[M,Nc] = A[M,K] @ W[K,Nc], 128x128 tile, 4 waves ---------
// MODE 0: plain bf16 A (vectorized copy)   MODE 4: plain f32 A (scalar)
// MODE 1: LN((Ab-mu)*rs)*lnS+lnB (bf16 A, vectorized)
// MODE 2: concat(Af[row,0:K1], Ab[row,0:256])       (skip layer, scalar)
// MODE 3: concat(Ab[row,0:256], Af[row/192,0:27])   (rgb1, scalar)
// rollShift (MODE<=1): A row n -> (n+rollShift)%192 within each sequence.
// Epilogue: acc(+bias)(+gelu) -> bf16 LDS tile -> coalesced 16B stores (+ADD).
template<int MODE, bool ADD, bool GELU>
__global__ __launch_bounds__(256) void gemm_mfma(
    const float* __restrict__ Af, const bf16* __restrict__ Ab, int lda, int aOff,
    const float* __restrict__ mu, const float* __restrict__ rs,
    const float* __restrict__ lnS, const float* __restrict__ lnB,
    const bf16* __restrict__ WT, int Kpad, const float* __restrict__ bias,
    bf16* __restrict__ C, int ldc, int cOff, int K, int K1, int rollShift)
{
  __shared__ short As[128*40];    // A tile [m][k], row pad 40
  __shared__ short Cs[128*136];   // C tile [m][n], row pad 136 (16B-aligned rows)
  const int tid = threadIdx.x;
  const int lane = tid & 63, wid = tid >> 6;
  const int wm = wid >> 1, wn = wid & 1;
  const int col16 = lane & 15, quad = lane >> 4;
  const int m0 = blockIdx.y * 128, n0 = blockIdx.x * 128;
  const int sm = tid >> 1, half = tid & 1;   // staging: row, k-half

  f32x4 acc[4][4];
  #pragma unroll
  for (int i = 0; i < 4; i++)
    #pragma unroll
    for (int j = 0; j < 4; j++) acc[i][j] = (f32x4){0.f,0.f,0.f,0.f};

  // staging source row
  int row = m0 + sm;
  if ((MODE == 0 || MODE == 1) && rollShift){
    int bb = row / NSEQ;
    int n  = row - bb*NSEQ;
    n += rollShift; if (n >= NSEQ) n -= NSEQ;
    row = bb*NSEQ + n;
  }
  const size_t arow = (size_t)aOff + row;
  float lnMu = 0.f, lnRs = 0.f;
  if (MODE == 1){ lnMu = mu[arow]; lnRs = rs[arow]; }

  for (int k0 = 0; k0 < Kpad; k0 += 32){
    // ---- stage A tile (128 x 32): thread covers (sm, half*16 + 0..15) ----
    if (MODE == 0){
      const uint4 u0 = *(const uint4*)(Ab + arow*lda + k0 + half*16);
      const uint4 u1 = *(const uint4*)(Ab + arow*lda + k0 + half*16 + 8);
      *(uint4*)&As[sm*40 + half*16]     = u0;
      *(uint4*)&As[sm*40 + half*16 + 8] = u1;
    } else if (MODE == 1){
      const uint4 u0 = *(const uint4*)(Ab + arow*lda + k0 + half*16);
      const uint4 u1 = *(const uint4*)(Ab + arow*lda + k0 + half*16 + 8);
      const unsigned uu[8] = {u0.x,u0.y,u0.z,u0.w,u1.x,u1.y,u1.z,u1.w};
      unsigned out[8];
      const int gkb = k0 + half*16;
      #pragma unroll
      for (int p = 0; p < 8; p++){
        int gk = gkb + 2*p;
        float a = (blo(uu[p]) - lnMu) * lnRs * lnS[gk]   + lnB[gk];
        float b = (bhi(uu[p]) - lnMu) * lnRs * lnS[gk+1] + lnB[gk+1];
        out[p] = pack2(a, b);
      }
      *(uint4*)&As[sm*40 + half*16]     = *(uint4*)&out[0];
      *(uint4*)&As[sm*40 + half*16 + 8] = *(uint4*)&out[4];
    } else {
      short tmp[16] __attribute__((aligned(16)));
      #pragma unroll
      for (int j = 0; j < 16; j++){
        int gk = k0 + half*16 + j;
        float v = 0.f;
        if (gk < K){
          if (MODE == 4)      v = Af[arow*lda + gk];
          else if (MODE == 2) v = (gk < K1) ? Af[arow*K1 + gk]
                                            : cvt(Ab[arow*256 + (gk-K1)]);
          else                v = (gk < K1) ? cvt(Ab[arow*256 + gk])
                                            : Af[(arow/NSEQ)*27 + (gk-K1)];
        }
        tmp[j] = bfbits(v);
      }
      *(short8*)&As[sm*40 + half*16]     = *(short8*)&tmp[0];
      *(short8*)&As[sm*40 + half*16 + 8] = *(short8*)&tmp[8];
    }
    __syncthreads();

    // ---- fragments + 16 MFMA ----
    short8 afr[4];
    #pragma unroll
    for (int mi = 0; mi < 4; mi++)
      afr[mi] = *(const short8*)&As[(wm*64 + mi*16 + col16)*40 + quad*8];
    short8 bfr[4];
    #pragma unroll
    for (int ni = 0; ni < 4; ni++)
      bfr[ni] = *(const short8*)((const short*)WT
                 + (size_t)(n0 + wn*64 + ni*16 + col16)*Kpad + k0 + quad*8);
    #pragma unroll
    for (int mi = 0; mi < 4; mi++)
      #pragma unroll
      for (int ni = 0; ni < 4; ni++)
        acc[mi][ni] = __builtin_amdgcn_mfma_f32_16x16x32_bf16(
            afr[mi], bfr[ni], acc[mi][ni], 0, 0, 0);
    __syncthreads();
  }

  // ---- epilogue phase 1: acc (+bias)(+gelu) -> Cs bf16 ----
  #pragma unroll
  for (int ni = 0; ni < 4; ni++){
    int ncol = wn*64 + ni*16 + col16;
    float bv = bias[n0 + ncol];
    #pragma unroll
    for (int mi = 0; mi < 4; mi++){
      f32x4 a = acc[mi][ni];
      #pragma unroll
      for (int r = 0; r < 4; r++){
        int lrow = wm*64 + mi*16 + quad*4 + r;
        float val = a[r] + bv;
        if (GELU) val = gelu_f(val);
        Cs[lrow*136 + ncol] = bfbits(val);
      }
    }
  }
  __syncthreads();

  // ---- epilogue phase 2: coalesced 16B stores (+ADD) ----
  const int orow = tid >> 4;         // 0..15
  const int ocol = (tid & 15) * 8;   // 0..120
  #pragma unroll
  for (int p = 0; p < 8; p++){
    int lrow = p*16 + orow;
    size_t mrow = (size_t)cOff + m0 + lrow;
    short8 v = *(const short8*)&Cs[lrow*136 + ocol];
    bf16* dst = C + mrow*ldc + n0 + ocol;
    if (ADD){
      short8 c = *(const short8*)dst;
      short8 o;
      #pragma unroll
      for (int e = 0; e < 8; e++){
        bf16 va, ca;
        *reinterpret_cast<short*>(&va) = v[e];
        *reinterpret_cast<short*>(&ca) = c[e];
        o[e] = bfbits(cvt(va) + cvt(ca));
      }
      *(short8*)dst = o;
    } else {
      *(short8*)dst = v;
    }
  }
}

// ---- lightweight windowed attention: softmax(QK^T/sqrt(hd)) @ V -----------
__global__ __launch_bounds__(256) void attn_lite(
    bf16* __restrict__ Qg, const bf16* __restrict__ Kg, const bf16* __restrict__ Vg)
{
  __shared__ float qs[8][257], ks[8][257], vs[8][257];
  __shared__ float sc[8][8][8];   // [h][q][k]
  const int c = threadIdx.x;
  const size_t base = (size_t)blockIdx.x * 8 * 256;
  #pragma unroll
  for (int j = 0; j < 8; j++){
    qs[j][c] = cvt(Qg[base + j*256 + c]);
    ks[j][c] = cvt(Kg[base + j*256 + c]);
    vs[j][c] = cvt(Vg[base + j*256 + c]);
  }
  __syncthreads();

  const float scale = 0.17677669529663687f; // 1/sqrt(32)
  #pragma unroll
  for (int r = 0; r < 2; r++){
    int idx = r*256 + c;
    int h = idx >> 6, qi = (idx >> 3) & 7, ki = idx & 7;
    float s = 0.f;
    #pragma unroll
    for (int d = 0; d < 32; d++) s += qs[qi][h*32+d] * ks[ki][h*32+d];
    sc[h][qi][ki] = s * scale;
  }
  __syncthreads();

  if (c < 64){
    int h = c >> 3, qi = c & 7;
    float mx = -1e30f;
    #pragma unroll
    for (int u = 0; u < 8; u++) mx = fmaxf(mx, sc[h][qi][u]);
    float e[8], sum = 0.f;
    #pragma unroll
    for (int u = 0; u < 8; u++){ e[u] = __expf(sc[h][qi][u] - mx); sum += e[u]; }
    float inv = 1.f / sum;
    #pragma unroll
    for (int u = 0; u < 8; u++) sc[h][qi][u] = e[u] * inv;
  }
  __syncthreads();

  {
    int h = c >> 5;
    #pragma unroll
    for (int j = 0; j < 8; j++){
      float o = 0.f;
      #pragma unroll
      for (int u = 0; u < 8; u++) o += sc[h][j][u] * vs[u][c];
      Qg[base + j*256 + c] = __float2bfloat16(o);
    }
  }
}

// ---- alpha head with fused ln_f: one wave per token (f32 out) -------------
__global__ __launch_bounds__(256) void alpha_kernel(
    const bf16* __restrict__ X, const float* __restrict__ mu,
    const float* __restrict__ rs, const float* __restrict__ s,
    const float* __restrict__ b, const float* __restrict__ wa,
    const float* __restrict__ ba, float* __restrict__ out)
{
  int lane = threadIdx.x & 63, w = threadIdx.x >> 6;
  size_t t = (size_t)blockIdx.x * 4 + w;
  float m = mu[t], r = rs[t];
  float acc = 0.f;
  #pragma unroll
  for (int j = 0; j < 4; j++){
    int c = lane + 64*j;
    float y = (cvt(X[t*DMODEL + c]) - m) * r * s[c] + b[c];
    acc += y * wa[c];
  }
  #pragma unroll
  for (int off = 32; off; off >>= 1) acc += __shfl_down(acc, off, 64);
  if (lane == 0) out[t] = acc + ba[0];
}

// ---- rgb2: t1 stored with ld=256 (cols 0..127), @ (128,3) + b (f32 out) ---
__global__ __launch_bounds__(256) void rgb2_kernel(
    const bf16* __restrict__ T1, const float* __restrict__ w2,
    const float* __restrict__ b2, float* __restrict__ out)
{
  int lane = threadIdx.x & 63, w = threadIdx.x >> 6;
  size_t t = (size_t)blockIdx.x * 4 + w;
  float h0 = cvt(T1[t*256 + lane]);
  float h1 = cvt(T1[t*256 + 64 + lane]);
  float a0 = h0*w2[lane*3+0] + h1*w2[(lane+64)*3+0];
  float a1 = h0*w2[lane*3+1] + h1*w2[(lane+64)*3+1];
  float a2 = h0*w2[lane*3+2] + h1*w2[(lane+64)*3+2];
  #pragma unroll
  for (int off = 32; off; off >>= 1){
    a0 += __shfl_down(a0, off, 64);
    a1 += __shfl_down(a1, off, 64);
    a2 += __shfl_down(a2, off, 64);
  }
  if (lane == 0){
    out[t*3+0] = a0 + b2[0];
    out[t*3+1] = a1 + b2[1];
    out[t*3+2] = a2 + b2[2];
  }
}

extern "C" void kernel_launch(void* const* d_in, const int* in_sizes, int n_in,
                              void* d_out, int out_size, void* d_ws, size_t ws_size,
                              hipStream_t stream)
{
  (void)in_sizes; (void)n_in; (void)out_size;
  const float* pts     = (const float*)d_in[0];
  const float* views   = (const float*)d_in[1];
  const float* w_in    = (const float*)d_in[2];
  const float* b_in    = (const float*)d_in[3];
  const float* ln_in_s = (const float*)d_in[4];
  const float* ln_in_b = (const float*)d_in[5];
  const float* ln1_s   = (const float*)d_in[6];
  const float* ln1_b   = (const float*)d_in[7];
  const float* wq      = (const float*)d_in[8];
  const float* bq      = (const float*)d_in[9];
  const float* wk      = (const float*)d_in[10];
  const float* bk      = (const float*)d_in[11];
  const float* wv      = (const float*)d_in[12];
  const float* bv      = (const float*)d_in[13];
  const float* wo      = (const float*)d_in[14];
  const float* bo      = (const float*)d_in[15];
  const float* ln2_s   = (const float*)d_in[16];
  const float* ln2_b   = (const float*)d_in[17];
  const float* w_mlp1  = (const float*)d_in[18];
  const float* b_mlp1  = (const float*)d_in[19];
  const float* w_mlp2  = (const float*)d_in[20];
  const float* b_mlp2  = (const float*)d_in[21];
  const float* w_skip  = (const float*)d_in[22];
  const float* b_skip  = (const float*)d_in[23];
  const float* ln_f_s  = (const float*)d_in[24];
  const float* ln_f_b  = (const float*)d_in[25];
  const float* w_alpha = (const float*)d_in[26];
  const float* b_alpha = (const float*)d_in[27];
  const float* w_feat  = (const float*)d_in[28];
  const float* b_feat  = (const float*)d_in[29];
  const float* w_rgb1  = (const float*)d_in[30];
  const float* b_rgb1  = (const float*)d_in[31];
  const float* w_rgb2  = (const float*)d_in[32];
  const float* b_rgb2  = (const float*)d_in[33];

  const size_t SZ = (size_t)T_TOK * DMODEL * 2;        // 100,663,296 B
  const size_t WT_ELEMS = 16384 + 2*(6*65536 + 81920) + 65536 + 36864;
  const size_t NEED = 2*SZ + (size_t)2*T_TOK*4 + WT_ELEMS*2;
  if (ws_size < NEED) return;

  char* wsp = (char*)d_ws;
  bf16* xr = (bf16*)(wsp);
  bf16* x2 = (bf16*)(wsp + SZ);
  float* mu = (float*)(wsp + 2*SZ);
  float* rs = mu + T_TOK;
  bf16* wtp = (bf16*)(wsp + 2*SZ + (size_t)2*T_TOK*4);

  // WT layout
  bf16* wt_in   = wtp;                       // 256 x 64
  bf16* wt_q[2], *wt_k[2], *wt_v[2], *wt_o[2], *wt_m1[2], *wt_m2[2], *wt_sk[2];
  bf16* p = wt_in + 16384;
  for (int i = 0; i < 2; i++){
    wt_q[i]  = p; p += 65536;
    wt_k[i]  = p; p += 65536;
    wt_v[i]  = p; p += 65536;
    wt_o[i]  = p; p += 65536;
    wt_m1[i] = p; p += 65536;
    wt_m2[i] = p; p += 65536;
    wt_sk[i] = p; p += 81920;                // 256 x 320
  }
  bf16* wt_feat = p; p += 65536;
  bf16* wt_rgb1 = p; p += 36864;             // 128 x 288

  float* out_rgb   = (float*)d_out;
  float* out_alpha = out_rgb + (size_t)T_TOK * 3;

  dim3 blk(256);
  dim3 g256(2, T_TOK/128);       // full-T, Nc=256
  dim3 gC(2, CHUNKM/128);        // chunk, Nc=256
  dim3 g128(1, T_TOK/128);       // full-T, Nc=128
  dim3 gTok(T_TOK);
  dim3 gStat(T_TOK/4);
  dim3 gAttn(CHUNKM/8);

  const float* NF = nullptr;
  const bf16*  NB = nullptr;

  // convert+transpose all weights to bf16 WT[N][Kpad]
  #define W2B(src, dst, K_, N_, KP_) \
    w2b_kernel<<<dim3(((N_)*(KP_)+255)/256), blk, 0, stream>>>(src, dst, K_, N_, KP_)
  W2B(w_in, wt_in, 63, 256, 64);
  for (int i = 0; i < 2; i++){
    W2B(wq + (size_t)i*65536, wt_q[i], 256, 256, 256);
    W2B(wk + (size_t)i*65536, wt_k[i], 256, 256, 256);
    W2B(wv + (size_t)i*65536, wt_v[i], 256, 256, 256);
    W2B(wo + (size_t)i*65536, wt_o[i], 256, 256, 256);
    W2B(w_mlp1 + (size_t)i*65536, wt_m1[i], 256, 256, 256);
    W2B(w_mlp2 + (size_t)i*65536, wt_m2[i], 256, 256, 256);
    W2B(w_skip + (size_t)i*81664, wt_sk[i], 319, 256, 320);
  }
  W2B(w_feat, wt_feat, 256, 256, 256);
  W2B(w_rgb1, wt_rgb1, 283, 128, 288);
  #undef W2B

  // x = pts @ w_in + b_in -> xr ; x = ln(x) + pe (in place)
  gemm_mfma<4,false,false><<<g256, blk, 0, stream>>>(pts, NB, 63, 0, NF, NF, NF, NF,
      wt_in, 64, b_in, xr, 256, 0, 63, 0, 0);
  ln_pe_kernel<<<gTok, blk, 0, stream>>>(xr, ln_in_s, ln_in_b);

  for (int i = 0; i < 2; i++){
    const int shift = (i == 1) ? 4 : 0;
    const int shiftBack = (i == 1) ? (NSEQ - 4) : 0;

    // ln1 stats over full residual
    ln_stats_kernel<<<gStat, blk, 0, stream>>>(xr, mu, rs);

    // attention, chunked: Q/K/V buffers live inside x2 (3 x 24 MB)
    bf16* qb = x2;
    bf16* kb = x2 + (size_t)CHUNKM * 256;
    bf16* vb = x2 + (size_t)2 * CHUNKM * 256;
    for (int cch = 0; cch < CHUNKS; cch++){
      int base = cch * CHUNKM;
      gemm_mfma<1,false,false><<<gC, blk, 0, stream>>>(NF, xr, 256, base, mu, rs,
          ln1_s + i*256, ln1_b + i*256, wt_q[i], 256, bq + i*256,
          qb, 256, 0, 256, 0, shift);
      gemm_mfma<1,false,false><<<gC, blk, 0, stream>>>(NF, xr, 256, base, mu, rs,
          ln1_s + i*256, ln1_b + i*256, wt_k[i], 256, bk + i*256,
          kb, 256, 0, 256, 0, shift);
      gemm_mfma<1,false,false><<<gC, blk, 0, stream>>>(NF, xr, 256, base, mu, rs,
          ln1_s + i*256, ln1_b + i*256, wt_v[i], 256, bv + i*256,
          vb, 256, 0, 256, 0, shift);
      attn_lite<<<gAttn, blk, 0, stream>>>(qb, kb, vb);
      // x_chunk += roll_back(O) @ wo + bo
      gemm_mfma<0,true,false><<<gC, blk, 0, stream>>>(NF, qb, 256, 0, NF, NF, NF, NF,
          wt_o[i], 256, bo + i*256, xr, 256, base, 256, 0, shiftBack);
    }

    // mlp
    ln_stats_kernel<<<gStat, blk, 0, stream>>>(xr, mu, rs);
    gemm_mfma<1,false,true ><<<g256, blk, 0, stream>>>(NF, xr, 256, 0, mu, rs,
        ln2_s + i*256, ln2_b + i*256, wt_m1[i], 256, b_mlp1 + i*256,
        x2, 256, 0, 256, 0, 0);
    gemm_mfma<0,true ,false><<<g256, blk, 0, stream>>>(NF, x2, 256, 0, NF, NF, NF, NF,
        wt_m2[i], 256, b_mlp2 + i*256, xr, 256, 0, 256, 0, 0);
    // x = gelu(concat(pts, x) @ w_skip + b_skip) -> x2, then swap
    gemm_mfma<2,false,true ><<<g256, blk, 0, stream>>>(pts, xr, 0, 0, NF, NF, NF, NF,
        wt_sk[i], 320, b_skip + i*256, x2, 256, 0, 319, 63, 0);
    bf16* tmp = xr; xr = x2; x2 = tmp;
  }

  // head
  ln_stats_kernel<<<gStat, blk, 0, stream>>>(xr, mu, rs);
  alpha_kernel<<<gStat, blk, 0, stream>>>(xr, mu, rs, ln_f_s, ln_f_b,
      w_alpha, b_alpha, out_alpha);
  // feature = ln_f(x) @ w_feat + b_feat -> x2
  gemm_mfma<1,false,false><<<g256, blk, 0, stream>>>(NF, xr, 256, 0, mu, rs,
      ln_f_s, ln_f_b, wt_feat, 256, b_feat, x2, 256, 0, 256, 0, 0);
  // t1 = gelu(concat(feature, views) @ w_rgb1 + b_rgb1) -> xr cols 0..127
  gemm_mfma<3,false,true ><<<g128, blk, 0, stream>>>(views, x2, 0, 0, NF, NF, NF, NF,
      wt_rgb1, 288, b_rgb1, xr, 256, 0, 283, 256, 0);
  rgb2_kernel<<<gStat, blk, 0, stream>>>(xr, w_rgb2, b_rgb2, out_rgb);
}

// Round 11
// 2415.391 us; speedup vs baseline: 7.7540x; 1.2386x over previous
//
#include <hip/hip_runtime.h>
#include <hip/hip_bf16.h>
#include <math.h>

typedef __hip_bfloat16 bf16;
typedef __attribute__((ext_vector_type(8))) short short8;
typedef __attribute__((ext_vector_type(4))) float f32x4;

#define T_TOK 196608   // B*N = 1024*192
#define NSEQ  192
#define DMODEL 256
#define CHUNKS 4
#define CHUNKM (T_TOK/CHUNKS)   // 49152 tokens = 256 sequences

__device__ __forceinline__ float cvt(float v){ return v; }
__device__ __forceinline__ float cvt(bf16 v){ return __bfloat162float(v); }
__device__ __forceinline__ short bfbits(float f){
  bf16 h = __float2bfloat16(f); return *reinterpret_cast<short*>(&h);
}
__device__ __forceinline__ float blo(unsigned u){ return __uint_as_float(u << 16); }
__device__ __forceinline__ float bhi(unsigned u){ return __uint_as_float(u & 0xffff0000u); }
__device__ __forceinline__ unsigned pack2(float a, float b){
  return ((unsigned)(unsigned short)bfbits(a)) | (((unsigned)(unsigned short)bfbits(b)) << 16);
}

__device__ __forceinline__ float gelu_f(float x){
  const float k0 = 0.7978845608028654f; // sqrt(2/pi)
  return 0.5f*x*(1.0f + tanhf(k0*(x + 0.044715f*x*x*x)));
}

// ---- weight convert+transpose into segment: dst[n*dstStride+kOff+k] ------
__global__ __launch_bounds__(256) void w2b_kernel(
    const float* __restrict__ src, bf16* __restrict__ dst,
    int K, int N, int KL, int dstStride, int kOff)
{
  int idx = blockIdx.x*256 + threadIdx.x;
  if (idx >= N*KL) return;
  int n = idx / KL, k = idx - n*KL;
  dst[(size_t)n*dstStride + kOff + k] =
      __float2bfloat16(k < K ? src[(size_t)k*N + n] : 0.f);
}

// ---- pts -> bf16 [T][64] zero-padded --------------------------------------
__global__ __launch_bounds__(256) void pts2b_kernel(
    const float* __restrict__ src, bf16* __restrict__ dst)
{
  int idx = blockIdx.x*256 + threadIdx.x;   // T*64
  int t = idx >> 6, k = idx & 63;
  dst[idx] = __float2bfloat16(k < 63 ? src[(size_t)t*63 + k] : 0.f);
}

// ---- views -> bf16 [1024][32] zero-padded ---------------------------------
__global__ __launch_bounds__(256) void views2b_kernel(
    const float* __restrict__ src, bf16* __restrict__ dst)
{
  int idx = blockIdx.x*256 + threadIdx.x;   // 1024*32
  int t = idx >> 5, k = idx & 31;
  dst[idx] = __float2bfloat16(k < 27 ? src[(size_t)t*27 + k] : 0.f);
}

// ---- bias concat [bq|bk|bv] -> dst[768] -----------------------------------
__global__ __launch_bounds__(256) void biascat_kernel(
    const float* __restrict__ b0, const float* __restrict__ b1,
    const float* __restrict__ b2, float* __restrict__ dst)
{
  int tid = threadIdx.x;
  const float* s = (blockIdx.x == 0) ? b0 : (blockIdx.x == 1) ? b1 : b2;
  dst[blockIdx.x*256 + tid] = s[tid];
}

// ---- per-token LN stats (wave per token, 4 tokens/block) ------------------
__global__ __launch_bounds__(256) void ln_stats_kernel(
    const bf16* __restrict__ X, float* __restrict__ mu, float* __restrict__ rsd)
{
  int lane = threadIdx.x & 63, w = threadIdx.x >> 6;
  size_t t = (size_t)blockIdx.x * 4 + w;
  float x[4];
  #pragma unroll
  for (int j = 0; j < 4; j++) x[j] = cvt(X[t*DMODEL + lane + 64*j]);
  float s = x[0] + x[1] + x[2] + x[3];
  #pragma unroll
  for (int off = 32; off; off >>= 1) s += __shfl_xor(s, off, 64);
  float m = s * (1.f/256.f);
  float q = 0.f;
  #pragma unroll
  for (int j = 0; j < 4; j++){ float d = x[j] - m; q += d*d; }
  #pragma unroll
  for (int off = 32; off; off >>= 1) q += __shfl_xor(q, off, 64);
  if (lane == 0){ mu[t] = m; rsd[t] = rsqrtf(q*(1.f/256.f) + 1e-6f); }
}

// ---- in-place: x = ln(x)*s+b + pos_embed  (block per token) ---------------
__global__ __launch_bounds__(256) void ln_pe_kernel(
    bf16* __restrict__ X, const float* __restrict__ s, const float* __restrict__ b)
{
  __shared__ float part[4];
  int t = blockIdx.x, d = threadIdx.x;
  int n = t % NSEQ;
  int lane = threadIdx.x & 63, w = threadIdx.x >> 6;
  float x = cvt(X[(size_t)t*DMODEL + d]);
  float v = x;
  #pragma unroll
  for (int off = 32; off; off >>= 1) v += __shfl_xor(v, off, 64);
  if (lane == 0) part[w] = v;
  __syncthreads();
  float mean = (part[0]+part[1]+part[2]+part[3]) * (1.f/256.f);
  float diff = x - mean;
  float vv = diff*diff;
  #pragma unroll
  for (int off = 32; off; off >>= 1) vv += __shfl_xor(vv, off, 64);
  __syncthreads();
  if (lane == 0) part[w] = vv;
  __syncthreads();
  float var = (part[0]+part[1]+part[2]+part[3]) * (1.f/256.f);
  float y = diff * rsqrtf(var + 1e-6f) * s[d] + b[d];
  float e = (float)(2*(d>>1)) / 256.f;
  float ang = (float)n * powf(10000.f, -e);
  y += (d & 1) ? cosf(ang) : sinf(ang);
  X[(size_t)t*DMODEL + d] = __float2bfloat16(y);
}

// ---- MFMA GEMM: C = A @ W, 128x128 tile, 4 waves, all-vectorized staging --
// MODE 0: plain bf16 A1
// MODE 1: LN((A1-mu)*rs)*lnS+lnB (bf16)
// MODE 2: two-segment concat: k<SB -> A1[arow][k], else A2[arow][k-SB]
// MODE 3: two-segment concat: k<SB -> A1[arow][k], else A2[arow/192][k-SB]
// rollShift (MODE<=1): A row n -> (n+rollShift)%192 within each sequence.
// C cols >=256 map to segment buffers: dst += (n0>>8)*segStride.
template<int MODE, bool ADD, bool GELU>
__global__ __launch_bounds__(256) void gemm_mfma(
    const bf16* __restrict__ A1, int lda1,
    const bf16* __restrict__ A2, int lda2, int SB, int aOff,
    const float* __restrict__ mu, const float* __restrict__ rs,
    const float* __restrict__ lnS, const float* __restrict__ lnB,
    const bf16* __restrict__ WT, int Kpad, const float* __restrict__ bias,
    bf16* __restrict__ C, int ldc, size_t segStride, int cOff, int rollShift)
{
  __shared__ short As[128*40];    // A tile [m][k], row pad 40
  __shared__ short Cs[128*136];   // C tile [m][n], row pad 136
  const int tid = threadIdx.x;
  const int lane = tid & 63, wid = tid >> 6;
  const int wm = wid >> 1, wn = wid & 1;
  const int col16 = lane & 15, quad = lane >> 4;
  const int m0 = blockIdx.y * 128, n0 = blockIdx.x * 128;
  const int sm = tid >> 1, half = tid & 1;   // staging: row, k-half

  f32x4 acc[4][4];
  #pragma unroll
  for (int i = 0; i < 4; i++)
    #pragma unroll
    for (int j = 0; j < 4; j++) acc[i][j] = (f32x4){0.f,0.f,0.f,0.f};

  // staging source row
  int row = m0 + sm;
  if (MODE <= 1 && rollShift){
    int bb = row / NSEQ;
    int n  = row - bb*NSEQ;
    n += rollShift; if (n >= NSEQ) n -= NSEQ;
    row = bb*NSEQ + n;
  }
  const size_t arow = (size_t)aOff + row;
  const size_t arow2 = (MODE == 3) ? (arow / NSEQ) : arow;
  float lnMu = 0.f, lnRs = 0.f;
  if (MODE == 1){ lnMu = mu[arow]; lnRs = rs[arow]; }

  for (int k0 = 0; k0 < Kpad; k0 += 32){
    const int gk = k0 + half*16;
    // ---- stage A tile (128 x 32): thread covers (sm, gk..gk+15) ----
    if (MODE == 1){
      const uint4 u0 = *(const uint4*)(A1 + arow*lda1 + gk);
      const uint4 u1 = *(const uint4*)(A1 + arow*lda1 + gk + 8);
      const unsigned uu[8] = {u0.x,u0.y,u0.z,u0.w,u1.x,u1.y,u1.z,u1.w};
      unsigned out[8];
      #pragma unroll
      for (int p = 0; p < 8; p++){
        int g = gk + 2*p;
        float a = (blo(uu[p]) - lnMu) * lnRs * lnS[g]   + lnB[g];
        float b = (bhi(uu[p]) - lnMu) * lnRs * lnS[g+1] + lnB[g+1];
        out[p] = pack2(a, b);
      }
      *(uint4*)&As[sm*40 + half*16]     = *(uint4*)&out[0];
      *(uint4*)&As[sm*40 + half*16 + 8] = *(uint4*)&out[4];
    } else {
      const bf16* src;
      if (MODE == 0) src = A1 + arow*lda1 + gk;
      else src = (gk < SB) ? (A1 + arow*(size_t)lda1 + gk)
                           : (A2 + arow2*(size_t)lda2 + (gk - SB));
      const uint4 u0 = *(const uint4*)(src);
      const uint4 u1 = *(const uint4*)(src + 8);
      *(uint4*)&As[sm*40 + half*16]     = u0;
      *(uint4*)&As[sm*40 + half*16 + 8] = u1;
    }
    __syncthreads();

    // ---- fragments + 16 MFMA ----
    short8 afr[4];
    #pragma unroll
    for (int mi = 0; mi < 4; mi++)
      afr[mi] = *(const short8*)&As[(wm*64 + mi*16 + col16)*40 + quad*8];
    short8 bfr[4];
    #pragma unroll
    for (int ni = 0; ni < 4; ni++)
      bfr[ni] = *(const short8*)((const short*)WT
                 + (size_t)(n0 + wn*64 + ni*16 + col16)*Kpad + k0 + quad*8);
    #pragma unroll
    for (int mi = 0; mi < 4; mi++)
      #pragma unroll
      for (int ni = 0; ni < 4; ni++)
        acc[mi][ni] = __builtin_amdgcn_mfma_f32_16x16x32_bf16(
            afr[mi], bfr[ni], acc[mi][ni], 0, 0, 0);
    __syncthreads();
  }

  // ---- epilogue phase 1: acc (+bias)(+gelu) -> Cs bf16 ----
  #pragma unroll
  for (int ni = 0; ni < 4; ni++){
    int ncol = wn*64 + ni*16 + col16;
    float bv = bias[n0 + ncol];
    #pragma unroll
    for (int mi = 0; mi < 4; mi++){
      f32x4 a = acc[mi][ni];
      #pragma unroll
      for (int r = 0; r < 4; r++){
        int lrow = wm*64 + mi*16 + quad*4 + r;
        float val = a[r] + bv;
        if (GELU) val = gelu_f(val);
        Cs[lrow*136 + ncol] = bfbits(val);
      }
    }
  }
  __syncthreads();

  // ---- epilogue phase 2: coalesced 16B stores (+ADD), C-segment remap ----
  const int seg = n0 >> 8;
  const int nb  = n0 & 255;
  const int orow = tid >> 4;         // 0..15
  const int ocol = (tid & 15) * 8;   // 0..120
  #pragma unroll
  for (int p = 0; p < 8; p++){
    int lrow = p*16 + orow;
    size_t mrow = (size_t)cOff + m0 + lrow;
    short8 v = *(const short8*)&Cs[lrow*136 + ocol];
    bf16* dst = C + (size_t)seg*segStride + mrow*ldc + nb + ocol;
    if (ADD){
      short8 c = *(const short8*)dst;
      short8 o;
      #pragma unroll
      for (int e = 0; e < 8; e++){
        bf16 va, ca;
        *reinterpret_cast<short*>(&va) = v[e];
        *reinterpret_cast<short*>(&ca) = c[e];
        o[e] = bfbits(cvt(va) + cvt(ca));
      }
      *(short8*)dst = o;
    } else {
      *(short8*)dst = v;
    }
  }
}

// ---- lightweight windowed attention: softmax(QK^T/sqrt(hd)) @ V -----------
__global__ __launch_bounds__(256) void attn_lite(
    bf16* __restrict__ Qg, const bf16* __restrict__ Kg, const bf16* __restrict__ Vg)
{
  __shared__ float qs[8][257], ks[8][257], vs[8][257];
  __shared__ float sc[8][8][8];   // [h][q][k]
  const int c = threadIdx.x;
  const size_t base = (size_t)blockIdx.x * 8 * 256;
  #pragma unroll
  for (int j = 0; j < 8; j++){
    qs[j][c] = cvt(Qg[base + j*256 + c]);
    ks[j][c] = cvt(Kg[base + j*256 + c]);
    vs[j][c] = cvt(Vg[base + j*256 + c]);
  }
  __syncthreads();

  const float scale = 0.17677669529663687f; // 1/sqrt(32)
  #pragma unroll
  for (int r = 0; r < 2; r++){
    int idx = r*256 + c;
    int h = idx >> 6, qi = (idx >> 3) & 7, ki = idx & 7;
    float s = 0.f;
    #pragma unroll
    for (int d = 0; d < 32; d++) s += qs[qi][h*32+d] * ks[ki][h*32+d];
    sc[h][qi][ki] = s * scale;
  }
  __syncthreads();

  if (c < 64){
    int h = c >> 3, qi = c & 7;
    float mx = -1e30f;
    #pragma unroll
    for (int u = 0; u < 8; u++) mx = fmaxf(mx, sc[h][qi][u]);
    float e[8], sum = 0.f;
    #pragma unroll
    for (int u = 0; u < 8; u++){ e[u] = __expf(sc[h][qi][u] - mx); sum += e[u]; }
    float inv = 1.f / sum;
    #pragma unroll
    for (int u = 0; u < 8; u++) sc[h][qi][u] = e[u] * inv;
  }
  __syncthreads();

  {
    int h = c >> 5;
    #pragma unroll
    for (int j = 0; j < 8; j++){
      float o = 0.f;
      #pragma unroll
      for (int u = 0; u < 8; u++) o += sc[h][j][u] * vs[u][c];
      Qg[base + j*256 + c] = __float2bfloat16(o);
    }
  }
}

// ---- alpha head with fused ln_f: one wave per token (f32 out) -------------
__global__ __launch_bounds__(256) void alpha_kernel(
    const bf16* __restrict__ X, const float* __restrict__ mu,
    const float* __restrict__ rs, const float* __restrict__ s,
    const float* __restrict__ b, const float* __restrict__ wa,
    const float* __restrict__ ba, float* __restrict__ out)
{
  int lane = threadIdx.x & 63, w = threadIdx.x >> 6;
  size_t t = (size_t)blockIdx.x * 4 + w;
  float m = mu[t], r = rs[t];
  float acc = 0.f;
  #pragma unroll
  for (int j = 0; j < 4; j++){
    int c = lane + 64*j;
    float y = (cvt(X[t*DMODEL + c]) - m) * r * s[c] + b[c];
    acc += y * wa[c];
  }
  #pragma unroll
  for (int off = 32; off; off >>= 1) acc += __shfl_down(acc, off, 64);
  if (lane == 0) out[t] = acc + ba[0];
}

// ---- rgb2: t1 stored with ld=256 (cols 0..127), @ (128,3) + b (f32 out) ---
__global__ __launch_bounds__(256) void rgb2_kernel(
    const bf16* __restrict__ T1, const float* __restrict__ w2,
    const float* __restrict__ b2, float* __restrict__ out)
{
  int lane = threadIdx.x & 63, w = threadIdx.x >> 6;
  size_t t = (size_t)blockIdx.x * 4 + w;
  float h0 = cvt(T1[t*256 + lane]);
  float h1 = cvt(T1[t*256 + 64 + lane]);
  float a0 = h0*w2[lane*3+0] + h1*w2[(lane+64)*3+0];
  float a1 = h0*w2[lane*3+1] + h1*w2[(lane+64)*3+1];
  float a2 = h0*w2[lane*3+2] + h1*w2[(lane+64)*3+2];
  #pragma unroll
  for (int off = 32; off; off >>= 1){
    a0 += __shfl_down(a0, off, 64);
    a1 += __shfl_down(a1, off, 64);
    a2 += __shfl_down(a2, off, 64);
  }
  if (lane == 0){
    out[t*3+0] = a0 + b2[0];
    out[t*3+1] = a1 + b2[1];
    out[t*3+2] = a2 + b2[2];
  }
}

extern "C" void kernel_launch(void* const* d_in, const int* in_sizes, int n_in,
                              void* d_out, int out_size, void* d_ws, size_t ws_size,
                              hipStream_t stream)
{
  (void)in_sizes; (void)n_in; (void)out_size;
  const float* pts     = (const float*)d_in[0];
  const float* views   = (const float*)d_in[1];
  const float* w_in    = (const float*)d_in[2];
  const float* b_in    = (const float*)d_in[3];
  const float* ln_in_s = (const float*)d_in[4];
  const float* ln_in_b = (const float*)d_in[5];
  const float* ln1_s   = (const float*)d_in[6];
  const float* ln1_b   = (const float*)d_in[7];
  const float* wq      = (const float*)d_in[8];
  const float* bq      = (const float*)d_in[9];
  const float* wk      = (const float*)d_in[10];
  const float* bk      = (const float*)d_in[11];
  const float* wv      = (const float*)d_in[12];
  const float* bv      = (const float*)d_in[13];
  const float* wo      = (const float*)d_in[14];
  const float* bo      = (const float*)d_in[15];
  const float* ln2_s   = (const float*)d_in[16];
  const float* ln2_b   = (const float*)d_in[17];
  const float* w_mlp1  = (const float*)d_in[18];
  const float* b_mlp1  = (const float*)d_in[19];
  const float* w_mlp2  = (const float*)d_in[20];
  const float* b_mlp2  = (const float*)d_in[21];
  const float* w_skip  = (const float*)d_in[22];
  const float* b_skip  = (const float*)d_in[23];
  const float* ln_f_s  = (const float*)d_in[24];
  const float* ln_f_b  = (const float*)d_in[25];
  const float* w_alpha = (const float*)d_in[26];
  const float* b_alpha = (const float*)d_in[27];
  const float* w_feat  = (const float*)d_in[28];
  const float* b_feat  = (const float*)d_in[29];
  const float* w_rgb1  = (const float*)d_in[30];
  const float* b_rgb1  = (const float*)d_in[31];
  const float* w_rgb2  = (const float*)d_in[32];
  const float* b_rgb2  = (const float*)d_in[33];

  const size_t SZ = (size_t)T_TOK * DMODEL * 2;        // 100,663,296 B
  // WT elems: wt_in 16384 + 2*(qkv 196608 + o/m1/m2 3*65536 + sk 81920)
  //           + feat 65536 + rgb1 36864
  const size_t WT_ELEMS = 16384 + 2*(196608 + 3*65536 + 81920) + 65536 + 36864;
  const size_t NEED = 2*SZ + (size_t)2*T_TOK*4 + 2*768*4 + WT_ELEMS*2
                    + (size_t)T_TOK*64*2 + 1024*32*2;
  if (ws_size < NEED) return;

  char* wsp = (char*)d_ws;
  bf16* xr = (bf16*)(wsp);
  bf16* x2 = (bf16*)(wsp + SZ);
  float* mu = (float*)(wsp + 2*SZ);
  float* rs = mu + T_TOK;
  float* bqkv = rs + T_TOK;                  // 2*768 floats
  bf16* wtp = (bf16*)(bqkv + 2*768);

  bf16* wt_in = wtp;                         // 256 x 64
  bf16* wt_qkv[2], *wt_o[2], *wt_m1[2], *wt_m2[2], *wt_sk[2];
  bf16* p = wt_in + 16384;
  for (int i = 0; i < 2; i++){
    wt_qkv[i] = p; p += 196608;              // 768 x 256
    wt_o[i]   = p; p += 65536;
    wt_m1[i]  = p; p += 65536;
    wt_m2[i]  = p; p += 65536;
    wt_sk[i]  = p; p += 81920;               // 256 x 320
  }
  bf16* wt_feat = p; p += 65536;
  bf16* wt_rgb1 = p; p += 36864;             // 128 x 288
  bf16* pts_b   = p; p += (size_t)T_TOK*64;  // T x 64
  bf16* views_b = p; p += 1024*32;

  float* out_rgb   = (float*)d_out;
  float* out_alpha = out_rgb + (size_t)T_TOK * 3;

  dim3 blk(256);
  dim3 g256(2, T_TOK/128);       // full-T, Nc=256
  dim3 gQKV(6, CHUNKM/128);      // chunk, Nc=768
  dim3 gC(2, CHUNKM/128);        // chunk, Nc=256
  dim3 g128(1, T_TOK/128);       // full-T, Nc=128
  dim3 gTok(T_TOK);
  dim3 gStat(T_TOK/4);
  dim3 gAttn(CHUNKM/8);

  const float* NF = nullptr;
  const bf16*  NB = nullptr;

  // ---- setup: pre-convert inputs & weights to bf16 ----
  pts2b_kernel<<<dim3(T_TOK*64/256), blk, 0, stream>>>(pts, pts_b);
  views2b_kernel<<<dim3(1024*32/256), blk, 0, stream>>>(views, views_b);
  #define W2B(src, dst, K_, N_, KL_, ST_, KO_) \
    w2b_kernel<<<dim3(((N_)*(KL_)+255)/256), blk, 0, stream>>>(src, dst, K_, N_, KL_, ST_, KO_)
  W2B(w_in, wt_in, 63, 256, 64, 64, 0);
  for (int i = 0; i < 2; i++){
    W2B(wq + (size_t)i*65536, wt_qkv[i],            256, 256, 256, 256, 0);
    W2B(wk + (size_t)i*65536, wt_qkv[i] + 65536,    256, 256, 256, 256, 0);
    W2B(wv + (size_t)i*65536, wt_qkv[i] + 131072,   256, 256, 256, 256, 0);
    W2B(wo + (size_t)i*65536, wt_o[i],  256, 256, 256, 256, 0);
    W2B(w_mlp1 + (size_t)i*65536, wt_m1[i], 256, 256, 256, 256, 0);
    W2B(w_mlp2 + (size_t)i*65536, wt_m2[i], 256, 256, 256, 256, 0);
    // skip: seg A = pts rows (63 of 64), seg B = x rows (256), Kpad 320
    W2B(w_skip + (size_t)i*81664,            wt_sk[i], 63, 256, 64, 320, 0);
    W2B(w_skip + (size_t)i*81664 + 63*256,   wt_sk[i], 256, 256, 256, 320, 64);
    biascat_kernel<<<dim3(3), blk, 0, stream>>>(bq + i*256, bk + i*256, bv + i*256,
        bqkv + i*768);
  }
  W2B(w_feat, wt_feat, 256, 256, 256, 256, 0);
  W2B(w_rgb1,                wt_rgb1, 256, 128, 256, 288, 0);
  W2B(w_rgb1 + 256*128,      wt_rgb1, 27, 128, 32, 288, 256);
  #undef W2B

  // x = pts @ w_in + b_in -> xr ; x = ln(x) + pe (in place)
  gemm_mfma<0,false,false><<<g256, blk, 0, stream>>>(pts_b, 64, NB, 0, 0, 0,
      NF, NF, NF, NF, wt_in, 64, b_in, xr, 256, 0, 0, 0);
  ln_pe_kernel<<<gTok, blk, 0, stream>>>(xr, ln_in_s, ln_in_b);

  for (int i = 0; i < 2; i++){
    const int shift = (i == 1) ? 4 : 0;
    const int shiftBack = (i == 1) ? (NSEQ - 4) : 0;

    ln_stats_kernel<<<gStat, blk, 0, stream>>>(xr, mu, rs);

    // attention, chunked: Q/K/V buffers live inside x2 (3 x 24 MB)
    bf16* qb = x2;
    bf16* kb = x2 + (size_t)CHUNKM * 256;
    bf16* vb = x2 + (size_t)2 * CHUNKM * 256;
    for (int cch = 0; cch < CHUNKS; cch++){
      int base = cch * CHUNKM;
      // fused q|k|v = ln1(roll(x_chunk)) @ wqkv + bqkv
      gemm_mfma<1,false,false><<<gQKV, blk, 0, stream>>>(xr, 256, NB, 0, 0, base,
          mu, rs, ln1_s + i*256, ln1_b + i*256, wt_qkv[i], 256, bqkv + i*768,
          x2, 256, (size_t)CHUNKM*256, 0, shift);
      attn_lite<<<gAttn, blk, 0, stream>>>(qb, kb, vb);
      // x_chunk += roll_back(O) @ wo + bo
      gemm_mfma<0,true,false><<<gC, blk, 0, stream>>>(qb, 256, NB, 0, 0, 0,
          NF, NF, NF, NF, wt_o[i], 256, bo + i*256, xr, 256, 0, base, shiftBack);
    }

    // mlp
    ln_stats_kernel<<<gStat, blk, 0, stream>>>(xr, mu, rs);
    gemm_mfma<1,false,true ><<<g256, blk, 0, stream>>>(xr, 256, NB, 0, 0, 0,
        mu, rs, ln2_s + i*256, ln2_b + i*256, wt_m1[i], 256, b_mlp1 + i*256,
        x2, 256, 0, 0, 0);
    gemm_mfma<0,true ,false><<<g256, blk, 0, stream>>>(x2, 256, NB, 0, 0, 0,
        NF, NF, NF, NF, wt_m2[i], 256, b_mlp2 + i*256, xr, 256, 0, 0, 0);
    // x = gelu(concat(pts, x) @ w_skip + b_skip) -> x2, then swap
    gemm_mfma<2,false,true ><<<g256, blk, 0, stream>>>(pts_b, 64, xr, 256, 64, 0,
        NF, NF, NF, NF, wt_sk[i], 320, b_skip + i*256, x2, 256, 0, 0, 0);
    bf16* tmp = xr; xr = x2; x2 = tmp;
  }

  // head
  ln_stats_kernel<<<gStat, blk, 0, stream>>>(xr, mu, rs);
  alpha_kernel<<<gStat, blk, 0, stream>>>(xr, mu, rs, ln_f_s, ln_f_b,
      w_alpha, b_alpha, out_alpha);
  // feature = ln_f(x) @ w_feat + b_feat -> x2
  gemm_mfma<1,false,false><<<g256, blk, 0, stream>>>(xr, 256, NB, 0, 0, 0,
      mu, rs, ln_f_s, ln_f_b, wt_feat, 256, b_feat, x2, 256, 0, 0, 0);
  // t1 = gelu(concat(feature, views) @ w_rgb1 + b_rgb1) -> xr cols 0..127
  gemm_mfma<3,false,true ><<<g128, blk, 0, stream>>>(x2, 256, views_b, 32, 256, 0,
      NF, NF, NF, NF, wt_rgb1, 288, b_rgb1, xr, 256, 0, 0, 0);
  rgb2_kernel<<<gStat, blk, 0, stream>>>(xr, w_rgb2, b_rgb2, out_rgb);
}

// Round 12
// 2313.686 us; speedup vs baseline: 8.0949x; 1.0440x over previous
//
#include <hip/hip_runtime.h>
#include <hip/hip_bf16.h>
#include <math.h>

typedef __hip_bfloat16 bf16;
typedef __attribute__((ext_vector_type(8))) short short8;
typedef __attribute__((ext_vector_type(4))) float f32x4;

#define T_TOK 196608   // B*N = 1024*192
#define NSEQ  192
#define DMODEL 256
#define CHUNKS 4
#define CHUNKM (T_TOK/CHUNKS)   // 49152 tokens = 256 sequences

__device__ __forceinline__ float cvt(float v){ return v; }
__device__ __forceinline__ float cvt(bf16 v){ return __bfloat162float(v); }
__device__ __forceinline__ short bfbits(float f){
  bf16 h = __float2bfloat16(f); return *reinterpret_cast<short*>(&h);
}
__device__ __forceinline__ float blo(unsigned u){ return __uint_as_float(u << 16); }
__device__ __forceinline__ float bhi(unsigned u){ return __uint_as_float(u & 0xffff0000u); }
__device__ __forceinline__ unsigned pack2(float a, float b){
  return ((unsigned)(unsigned short)bfbits(a)) | (((unsigned)(unsigned short)bfbits(b)) << 16);
}

__device__ __forceinline__ float gelu_f(float x){
  const float k0 = 0.7978845608028654f; // sqrt(2/pi)
  return 0.5f*x*(1.0f + tanhf(k0*(x + 0.044715f*x*x*x)));
}

// block-wide sum over 256 threads; part = shared float[4]
__device__ __forceinline__ float bsum(float v, float* part){
  int lane = threadIdx.x & 63, w = threadIdx.x >> 6;
  #pragma unroll
  for (int off = 32; off; off >>= 1) v += __shfl_xor(v, off, 64);
  __syncthreads();
  if (lane == 0) part[w] = v;
  __syncthreads();
  return part[0] + part[1] + part[2] + part[3];
}

// ---- pos-embed table: PE[n][d], n<192 ------------------------------------
__global__ __launch_bounds__(256) void pe_kernel(float* __restrict__ PE){
  int n = blockIdx.x, d = threadIdx.x;
  float e = (float)(2*(d>>1)) / 256.f;
  float ang = (float)n * powf(10000.f, -e);
  PE[n*DMODEL + d] = (d & 1) ? cosf(ang) : sinf(ang);
}

// ---- weight convert+transpose into segment: dst[n*dstStride+kOff+k] ------
__global__ __launch_bounds__(256) void w2b_kernel(
    const float* __restrict__ src, bf16* __restrict__ dst,
    int K, int N, int KL, int dstStride, int kOff)
{
  int idx = blockIdx.x*256 + threadIdx.x;
  if (idx >= N*KL) return;
  int n = idx / KL, k = idx - n*KL;
  dst[(size_t)n*dstStride + kOff + k] =
      __float2bfloat16(k < K ? src[(size_t)k*N + n] : 0.f);
}

// ---- pts -> bf16 [T][64] zero-padded --------------------------------------
__global__ __launch_bounds__(256) void pts2b_kernel(
    const float* __restrict__ src, bf16* __restrict__ dst)
{
  int idx = blockIdx.x*256 + threadIdx.x;   // T*64
  int t = idx >> 6, k = idx & 63;
  dst[idx] = __float2bfloat16(k < 63 ? src[(size_t)t*63 + k] : 0.f);
}

// ---- views -> bf16 [1024][32] zero-padded ---------------------------------
__global__ __launch_bounds__(256) void views2b_kernel(
    const float* __restrict__ src, bf16* __restrict__ dst)
{
  int idx = blockIdx.x*256 + threadIdx.x;   // 1024*32
  int t = idx >> 5, k = idx & 31;
  dst[idx] = __float2bfloat16(k < 27 ? src[(size_t)t*27 + k] : 0.f);
}

// ---- bias concat [bq|bk|bv] -> dst[768] -----------------------------------
__global__ __launch_bounds__(256) void biascat_kernel(
    const float* __restrict__ b0, const float* __restrict__ b1,
    const float* __restrict__ b2, float* __restrict__ dst)
{
  int tid = threadIdx.x;
  const float* s = (blockIdx.x == 0) ? b0 : (blockIdx.x == 1) ? b1 : b2;
  dst[blockIdx.x*256 + tid] = s[tid];
}

// ---- in-place: x = ln(x)*s+b + PE[n]; writes raw stats (s1=Σy, s2=Σy²) ----
__global__ __launch_bounds__(256) void ln_pe_kernel(
    bf16* __restrict__ X, const float* __restrict__ s, const float* __restrict__ b,
    const float* __restrict__ PE, float* __restrict__ s1o, float* __restrict__ s2o)
{
  __shared__ float part[4];
  int t = blockIdx.x, d = threadIdx.x;
  int n = t % NSEQ;
  float x = cvt(X[(size_t)t*DMODEL + d]);
  float mean = bsum(x, part) * (1.f/256.f);
  float diff = x - mean;
  float var = bsum(diff*diff, part) * (1.f/256.f);
  float y = diff * rsqrtf(var + 1e-6f) * s[d] + b[d] + PE[n*DMODEL + d];
  X[(size_t)t*DMODEL + d] = __float2bfloat16(y);
  float s1 = bsum(y, part);
  float s2 = bsum(y*y, part);
  if (threadIdx.x == 0){ s1o[t] = s1; s2o[t] = s2; }
}

// ---- MFMA GEMM: C = A @ W, 128x128 tile, 4 waves, vectorized staging ------
// MODE 0: plain bf16 A1
// MODE 1: LN via raw sums s1i/s2i: ((A1-mu)*rstd)*lnS+lnB
// MODE 2: two-segment concat: k<SB -> A1[arow][k], else A2[arow][k-SB]
// MODE 3: two-segment concat: k<SB -> A1[arow][k], else A2[arow/192][k-SB]
// rollShift (MODE<=1): A row n -> (n+rollShift)%192 within each sequence.
// C cols >=256 map to segment buffers: dst += (n0>>8)*segStride.
// STATS: per-row Σ and Σ² of final C values atomically added to s1o/s2o.
template<int MODE, bool ADD, bool GELU, bool STATS>
__global__ __launch_bounds__(256) void gemm_mfma(
    const bf16* __restrict__ A1, int lda1,
    const bf16* __restrict__ A2, int lda2, int SB, int aOff,
    const float* __restrict__ s1i, const float* __restrict__ s2i,
    const float* __restrict__ lnS, const float* __restrict__ lnB,
    const bf16* __restrict__ WT, int Kpad, const float* __restrict__ bias,
    bf16* __restrict__ C, int ldc, size_t segStride, int cOff, int rollShift,
    float* __restrict__ s1o, float* __restrict__ s2o)
{
  __shared__ short As[128*40];    // A tile [m][k], row pad 40
  __shared__ short Cs[128*136];   // C tile [m][n], row pad 136
  const int tid = threadIdx.x;
  const int lane = tid & 63, wid = tid >> 6;
  const int wm = wid >> 1, wn = wid & 1;
  const int col16 = lane & 15, quad = lane >> 4;
  const int m0 = blockIdx.y * 128, n0 = blockIdx.x * 128;
  const int sm = tid >> 1, half = tid & 1;   // staging: row, k-half

  f32x4 acc[4][4];
  #pragma unroll
  for (int i = 0; i < 4; i++)
    #pragma unroll
    for (int j = 0; j < 4; j++) acc[i][j] = (f32x4){0.f,0.f,0.f,0.f};

  // staging source row
  int row = m0 + sm;
  if (MODE <= 1 && rollShift){
    int bb = row / NSEQ;
    int n  = row - bb*NSEQ;
    n += rollShift; if (n >= NSEQ) n -= NSEQ;
    row = bb*NSEQ + n;
  }
  const size_t arow = (size_t)aOff + row;
  const size_t arow2 = (MODE == 3) ? (arow / NSEQ) : arow;
  float lnMu = 0.f, lnRs = 0.f;
  if (MODE == 1){
    float m1 = s1i[arow] * (1.f/256.f);
    float m2 = s2i[arow] * (1.f/256.f);
    lnMu = m1;
    lnRs = rsqrtf(m2 - m1*m1 + 1e-6f);
  }

  for (int k0 = 0; k0 < Kpad; k0 += 32){
    const int gk = k0 + half*16;
    // ---- stage A tile (128 x 32): thread covers (sm, gk..gk+15) ----
    if (MODE == 1){
      const uint4 u0 = *(const uint4*)(A1 + arow*lda1 + gk);
      const uint4 u1 = *(const uint4*)(A1 + arow*lda1 + gk + 8);
      const unsigned uu[8] = {u0.x,u0.y,u0.z,u0.w,u1.x,u1.y,u1.z,u1.w};
      unsigned out[8];
      #pragma unroll
      for (int p = 0; p < 8; p++){
        int g = gk + 2*p;
        float a = (blo(uu[p]) - lnMu) * lnRs * lnS[g]   + lnB[g];
        float b = (bhi(uu[p]) - lnMu) * lnRs * lnS[g+1] + lnB[g+1];
        out[p] = pack2(a, b);
      }
      *(uint4*)&As[sm*40 + half*16]     = *(uint4*)&out[0];
      *(uint4*)&As[sm*40 + half*16 + 8] = *(uint4*)&out[4];
    } else {
      const bf16* src;
      if (MODE == 0) src = A1 + arow*lda1 + gk;
      else src = (gk < SB) ? (A1 + arow*(size_t)lda1 + gk)
                           : (A2 + arow2*(size_t)lda2 + (gk - SB));
      const uint4 u0 = *(const uint4*)(src);
      const uint4 u1 = *(const uint4*)(src + 8);
      *(uint4*)&As[sm*40 + half*16]     = u0;
      *(uint4*)&As[sm*40 + half*16 + 8] = u1;
    }
    __syncthreads();

    // ---- fragments + 16 MFMA ----
    short8 afr[4];
    #pragma unroll
    for (int mi = 0; mi < 4; mi++)
      afr[mi] = *(const short8*)&As[(wm*64 + mi*16 + col16)*40 + quad*8];
    short8 bfr[4];
    #pragma unroll
    for (int ni = 0; ni < 4; ni++)
      bfr[ni] = *(const short8*)((const short*)WT
                 + (size_t)(n0 + wn*64 + ni*16 + col16)*Kpad + k0 + quad*8);
    #pragma unroll
    for (int mi = 0; mi < 4; mi++)
      #pragma unroll
      for (int ni = 0; ni < 4; ni++)
        acc[mi][ni] = __builtin_amdgcn_mfma_f32_16x16x32_bf16(
            afr[mi], bfr[ni], acc[mi][ni], 0, 0, 0);
    __syncthreads();
  }

  // ---- epilogue phase 1: acc (+bias)(+gelu) -> Cs bf16 ----
  #pragma unroll
  for (int ni = 0; ni < 4; ni++){
    int ncol = wn*64 + ni*16 + col16;
    float bv = bias[n0 + ncol];
    #pragma unroll
    for (int mi = 0; mi < 4; mi++){
      f32x4 a = acc[mi][ni];
      #pragma unroll
      for (int r = 0; r < 4; r++){
        int lrow = wm*64 + mi*16 + quad*4 + r;
        float val = a[r] + bv;
        if (GELU) val = gelu_f(val);
        Cs[lrow*136 + ncol] = bfbits(val);
      }
    }
  }
  __syncthreads();

  // ---- epilogue phase 2: coalesced 16B stores (+ADD) (+STATS) ----
  const int seg = n0 >> 8;
  const int nb  = n0 & 255;
  const int orow = tid >> 4;         // 0..15
  const int ocol = (tid & 15) * 8;   // 0..120
  #pragma unroll
  for (int p = 0; p < 8; p++){
    int lrow = p*16 + orow;
    size_t mrow = (size_t)cOff + m0 + lrow;
    short8 v = *(const short8*)&Cs[lrow*136 + ocol];
    bf16* dst = C + (size_t)seg*segStride + mrow*ldc + nb + ocol;
    float rowSum = 0.f, rowSq = 0.f;
    if (ADD){
      short8 c = *(const short8*)dst;
      short8 o;
      #pragma unroll
      for (int e = 0; e < 8; e++){
        bf16 va, ca;
        *reinterpret_cast<short*>(&va) = v[e];
        *reinterpret_cast<short*>(&ca) = c[e];
        float f = cvt(va) + cvt(ca);
        o[e] = bfbits(f);
        if (STATS){ rowSum += f; rowSq += f*f; }
      }
      *(short8*)dst = o;
    } else {
      if (STATS){
        #pragma unroll
        for (int e = 0; e < 8; e++){
          bf16 va; *reinterpret_cast<short*>(&va) = v[e];
          float f = cvt(va);
          rowSum += f; rowSq += f*f;
        }
      }
      *(short8*)dst = v;
    }
    if (STATS){
      #pragma unroll
      for (int mk = 1; mk <= 8; mk <<= 1){
        rowSum += __shfl_xor(rowSum, mk, 64);
        rowSq  += __shfl_xor(rowSq,  mk, 64);
      }
      if ((tid & 15) == 0){
        atomicAdd(&s1o[mrow], rowSum);
        atomicAdd(&s2o[mrow], rowSq);
      }
    }
  }
}

// ---- lightweight windowed attention: softmax(QK^T/sqrt(hd)) @ V -----------
__global__ __launch_bounds__(256) void attn_lite(
    bf16* __restrict__ Qg, const bf16* __restrict__ Kg, const bf16* __restrict__ Vg)
{
  __shared__ float qs[8][257], ks[8][257], vs[8][257];
  __shared__ float sc[8][8][8];   // [h][q][k]
  const int c = threadIdx.x;
  const size_t base = (size_t)blockIdx.x * 8 * 256;
  #pragma unroll
  for (int j = 0; j < 8; j++){
    qs[j][c] = cvt(Qg[base + j*256 + c]);
    ks[j][c] = cvt(Kg[base + j*256 + c]);
    vs[j][c] = cvt(Vg[base + j*256 + c]);
  }
  __syncthreads();

  const float scale = 0.17677669529663687f; // 1/sqrt(32)
  #pragma unroll
  for (int r = 0; r < 2; r++){
    int idx = r*256 + c;
    int h = idx >> 6, qi = (idx >> 3) & 7, ki = idx & 7;
    float s = 0.f;
    #pragma unroll
    for (int d = 0; d < 32; d++) s += qs[qi][h*32+d] * ks[ki][h*32+d];
    sc[h][qi][ki] = s * scale;
  }
  __syncthreads();

  if (c < 64){
    int h = c >> 3, qi = c & 7;
    float mx = -1e30f;
    #pragma unroll
    for (int u = 0; u < 8; u++) mx = fmaxf(mx, sc[h][qi][u]);
    float e[8], sum = 0.f;
    #pragma unroll
    for (int u = 0; u < 8; u++){ e[u] = __expf(sc[h][qi][u] - mx); sum += e[u]; }
    float inv = 1.f / sum;
    #pragma unroll
    for (int u = 0; u < 8; u++) sc[h][qi][u] = e[u] * inv;
  }
  __syncthreads();

  {
    int h = c >> 5;
    #pragma unroll
    for (int j = 0; j < 8; j++){
      float o = 0.f;
      #pragma unroll
      for (int u = 0; u < 8; u++) o += sc[h][j][u] * vs[u][c];
      Qg[base + j*256 + c] = __float2bfloat16(o);
    }
  }
}

// ---- alpha head with fused ln_f (raw sums): one wave per token ------------
__global__ __launch_bounds__(256) void alpha_kernel(
    const bf16* __restrict__ X, const float* __restrict__ s1,
    const float* __restrict__ s2, const float* __restrict__ s,
    const float* __restrict__ b, const float* __restrict__ wa,
    const float* __restrict__ ba, float* __restrict__ out)
{
  int lane = threadIdx.x & 63, w = threadIdx.x >> 6;
  size_t t = (size_t)blockIdx.x * 4 + w;
  float m = s1[t] * (1.f/256.f);
  float q = s2[t] * (1.f/256.f);
  float r = rsqrtf(q - m*m + 1e-6f);
  float acc = 0.f;
  #pragma unroll
  for (int j = 0; j < 4; j++){
    int c = lane + 64*j;
    float y = (cvt(X[t*DMODEL + c]) - m) * r * s[c] + b[c];
    acc += y * wa[c];
  }
  #pragma unroll
  for (int off = 32; off; off >>= 1) acc += __shfl_down(acc, off, 64);
  if (lane == 0) out[t] = acc + ba[0];
}

// ---- rgb2: t1 stored with ld=256 (cols 0..127), @ (128,3) + b (f32 out) ---
__global__ __launch_bounds__(256) void rgb2_kernel(
    const bf16* __restrict__ T1, const float* __restrict__ w2,
    const float* __restrict__ b2, float* __restrict__ out)
{
  int lane = threadIdx.x & 63, w = threadIdx.x >> 6;
  size_t t = (size_t)blockIdx.x * 4 + w;
  float h0 = cvt(T1[t*256 + lane]);
  float h1 = cvt(T1[t*256 + 64 + lane]);
  float a0 = h0*w2[lane*3+0] + h1*w2[(lane+64)*3+0];
  float a1 = h0*w2[lane*3+1] + h1*w2[(lane+64)*3+1];
  float a2 = h0*w2[lane*3+2] + h1*w2[(lane+64)*3+2];
  #pragma unroll
  for (int off = 32; off; off >>= 1){
    a0 += __shfl_down(a0, off, 64);
    a1 += __shfl_down(a1, off, 64);
    a2 += __shfl_down(a2, off, 64);
  }
  if (lane == 0){
    out[t*3+0] = a0 + b2[0];
    out[t*3+1] = a1 + b2[1];
    out[t*3+2] = a2 + b2[2];
  }
}

extern "C" void kernel_launch(void* const* d_in, const int* in_sizes, int n_in,
                              void* d_out, int out_size, void* d_ws, size_t ws_size,
                              hipStream_t stream)
{
  (void)in_sizes; (void)n_in; (void)out_size;
  const float* pts     = (const float*)d_in[0];
  const float* views   = (const float*)d_in[1];
  const float* w_in    = (const float*)d_in[2];
  const float* b_in    = (const float*)d_in[3];
  const float* ln_in_s = (const float*)d_in[4];
  const float* ln_in_b = (const float*)d_in[5];
  const float* ln1_s   = (const float*)d_in[6];
  const float* ln1_b   = (const float*)d_in[7];
  const float* wq      = (const float*)d_in[8];
  const float* bq      = (const float*)d_in[9];
  const float* wk      = (const float*)d_in[10];
  const float* bk      = (const float*)d_in[11];
  const float* wv      = (const float*)d_in[12];
  const float* bv      = (const float*)d_in[13];
  const float* wo      = (const float*)d_in[14];
  const float* bo      = (const float*)d_in[15];
  const float* ln2_s   = (const float*)d_in[16];
  const float* ln2_b   = (const float*)d_in[17];
  const float* w_mlp1  = (const float*)d_in[18];
  const float* b_mlp1  = (const float*)d_in[19];
  const float* w_mlp2  = (const float*)d_in[20];
  const float* b_mlp2  = (const float*)d_in[21];
  const float* w_skip  = (const float*)d_in[22];
  const float* b_skip  = (const float*)d_in[23];
  const float* ln_f_s  = (const float*)d_in[24];
  const float* ln_f_b  = (const float*)d_in[25];
  const float* w_alpha = (const float*)d_in[26];
  const float* b_alpha = (const float*)d_in[27];
  const float* w_feat  = (const float*)d_in[28];
  const float* b_feat  = (const float*)d_in[29];
  const float* w_rgb1  = (const float*)d_in[30];
  const float* b_rgb1  = (const float*)d_in[31];
  const float* w_rgb2  = (const float*)d_in[32];
  const float* b_rgb2  = (const float*)d_in[33];

  const size_t SZ = (size_t)T_TOK * DMODEL * 2;        // 100,663,296 B
  const size_t WT_ELEMS = 16384 + 2*(196608 + 3*65536 + 81920) + 65536 + 36864;
  const size_t NEED = 2*SZ + (size_t)4*T_TOK*4 + NSEQ*DMODEL*4 + 2*768*4
                    + WT_ELEMS*2 + (size_t)T_TOK*64*2 + 1024*32*2;
  if (ws_size < NEED) return;

  char* wsp = (char*)d_ws;
  bf16* xr = (bf16*)(wsp);
  bf16* x2 = (bf16*)(wsp + SZ);
  float* s1A = (float*)(wsp + 2*SZ);
  float* s2A = s1A + T_TOK;
  float* s1B = s2A + T_TOK;
  float* s2B = s1B + T_TOK;
  float* PE  = s2B + T_TOK;                  // 192*256 floats
  float* bqkv = PE + NSEQ*DMODEL;            // 2*768 floats
  bf16* wtp = (bf16*)(bqkv + 2*768);

  bf16* wt_in = wtp;                         // 256 x 64
  bf16* wt_qkv[2], *wt_o[2], *wt_m1[2], *wt_m2[2], *wt_sk[2];
  bf16* p = wt_in + 16384;
  for (int i = 0; i < 2; i++){
    wt_qkv[i] = p; p += 196608;              // 768 x 256
    wt_o[i]   = p; p += 65536;
    wt_m1[i]  = p; p += 65536;
    wt_m2[i]  = p; p += 65536;
    wt_sk[i]  = p; p += 81920;               // 256 x 320
  }
  bf16* wt_feat = p; p += 65536;
  bf16* wt_rgb1 = p; p += 36864;             // 128 x 288
  bf16* pts_b   = p; p += (size_t)T_TOK*64;  // T x 64
  bf16* views_b = p; p += 1024*32;

  float* out_rgb   = (float*)d_out;
  float* out_alpha = out_rgb + (size_t)T_TOK * 3;

  dim3 blk(256);
  dim3 g256(2, T_TOK/128);       // full-T, Nc=256
  dim3 gQKV(6, CHUNKM/128);      // chunk, Nc=768
  dim3 gC(2, CHUNKM/128);        // chunk, Nc=256
  dim3 g128(1, T_TOK/128);       // full-T, Nc=128
  dim3 gTok(T_TOK);
  dim3 gStat(T_TOK/4);
  dim3 gAttn(CHUNKM/8);

  const float* NF = nullptr;
  const bf16*  NB = nullptr;
  float* NFW = nullptr;

  // ---- setup: PE table, pre-convert inputs & weights to bf16 ----
  pe_kernel<<<dim3(NSEQ), blk, 0, stream>>>(PE);
  pts2b_kernel<<<dim3(T_TOK*64/256), blk, 0, stream>>>(pts, pts_b);
  views2b_kernel<<<dim3(1024*32/256), blk, 0, stream>>>(views, views_b);
  #define W2B(src, dst, K_, N_, KL_, ST_, KO_) \
    w2b_kernel<<<dim3(((N_)*(KL_)+255)/256), blk, 0, stream>>>(src, dst, K_, N_, KL_, ST_, KO_)
  W2B(w_in, wt_in, 63, 256, 64, 64, 0);
  for (int i = 0; i < 2; i++){
    W2B(wq + (size_t)i*65536, wt_qkv[i],            256, 256, 256, 256, 0);
    W2B(wk + (size_t)i*65536, wt_qkv[i] + 65536,    256, 256, 256, 256, 0);
    W2B(wv + (size_t)i*65536, wt_qkv[i] + 131072,   256, 256, 256, 256, 0);
    W2B(wo + (size_t)i*65536, wt_o[i],  256, 256, 256, 256, 0);
    W2B(w_mlp1 + (size_t)i*65536, wt_m1[i], 256, 256, 256, 256, 0);
    W2B(w_mlp2 + (size_t)i*65536, wt_m2[i], 256, 256, 256, 256, 0);
    W2B(w_skip + (size_t)i*81664,            wt_sk[i], 63, 256, 64, 320, 0);
    W2B(w_skip + (size_t)i*81664 + 63*256,   wt_sk[i], 256, 256, 256, 320, 64);
    biascat_kernel<<<dim3(3), blk, 0, stream>>>(bq + i*256, bk + i*256, bv + i*256,
        bqkv + i*768);
  }
  W2B(w_feat, wt_feat, 256, 256, 256, 256, 0);
  W2B(w_rgb1,                wt_rgb1, 256, 128, 256, 288, 0);
  W2B(w_rgb1 + 256*128,      wt_rgb1, 27, 128, 32, 288, 256);
  #undef W2B

  // x = pts @ w_in + b_in -> xr ; x = ln(x) + pe (in place, stats -> A)
  gemm_mfma<0,false,false,false><<<g256, blk, 0, stream>>>(pts_b, 64, NB, 0, 0, 0,
      NF, NF, NF, NF, wt_in, 64, b_in, xr, 256, 0, 0, 0, NFW, NFW);
  ln_pe_kernel<<<gTok, blk, 0, stream>>>(xr, ln_in_s, ln_in_b, PE, s1A, s2A);

  for (int i = 0; i < 2; i++){
    const int shift = (i == 1) ? 4 : 0;
    const int shiftBack = (i == 1) ? (NSEQ - 4) : 0;

    // zero ln2-stats accumulators
    hipMemsetAsync(s1B, 0, (size_t)2*T_TOK*4, stream);

    // attention, chunked: Q/K/V buffers live inside x2 (3 x 24 MB)
    bf16* qb = x2;
    bf16* kb = x2 + (size_t)CHUNKM * 256;
    bf16* vb = x2 + (size_t)2 * CHUNKM * 256;
    for (int cch = 0; cch < CHUNKS; cch++){
      int base = cch * CHUNKM;
      // fused q|k|v = ln1(roll(x_chunk)) @ wqkv + bqkv   (LN from stats A)
      gemm_mfma<1,false,false,false><<<gQKV, blk, 0, stream>>>(xr, 256, NB, 0, 0, base,
          s1A, s2A, ln1_s + i*256, ln1_b + i*256, wt_qkv[i], 256, bqkv + i*768,
          x2, 256, (size_t)CHUNKM*256, 0, shift, NFW, NFW);
      attn_lite<<<gAttn, blk, 0, stream>>>(qb, kb, vb);
      // x_chunk += roll_back(O) @ wo + bo   (stats -> B)
      gemm_mfma<0,true,false,true><<<gC, blk, 0, stream>>>(qb, 256, NB, 0, 0, 0,
          NF, NF, NF, NF, wt_o[i], 256, bo + i*256, xr, 256, 0, base, shiftBack,
          s1B, s2B);
    }

    // mlp (ln2 from stats B)
    gemm_mfma<1,false,true ,false><<<g256, blk, 0, stream>>>(xr, 256, NB, 0, 0, 0,
        s1B, s2B, ln2_s + i*256, ln2_b + i*256, wt_m1[i], 256, b_mlp1 + i*256,
        x2, 256, 0, 0, 0, NFW, NFW);
    gemm_mfma<0,true ,false,false><<<g256, blk, 0, stream>>>(x2, 256, NB, 0, 0, 0,
        NF, NF, NF, NF, wt_m2[i], 256, b_mlp2 + i*256, xr, 256, 0, 0, 0, NFW, NFW);
    // x = gelu(concat(pts, x) @ w_skip + b_skip) -> x2 (stats -> A), swap
    hipMemsetAsync(s1A, 0, (size_t)2*T_TOK*4, stream);
    gemm_mfma<2,false,true ,true><<<g256, blk, 0, stream>>>(pts_b, 64, xr, 256, 64, 0,
        NF, NF, NF, NF, wt_sk[i], 320, b_skip + i*256, x2, 256, 0, 0, 0,
        s1A, s2A);
    bf16* tmp = xr; xr = x2; x2 = tmp;
  }

  // head (ln_f from stats A)
  alpha_kernel<<<gStat, blk, 0, stream>>>(xr, s1A, s2A, ln_f_s, ln_f_b,
      w_alpha, b_alpha, out_alpha);
  // feature = ln_f(x) @ w_feat + b_feat -> x2
  gemm_mfma<1,false,false,false><<<g256, blk, 0, stream>>>(xr, 256, NB, 0, 0, 0,
      s1A, s2A, ln_f_s, ln_f_b, wt_feat, 256, b_feat, x2, 256, 0, 0, 0, NFW, NFW);
  // t1 = gelu(concat(feature, views) @ w_rgb1 + b_rgb1) -> xr cols 0..127
  gemm_mfma<3,false,true ,false><<<g128, blk, 0, stream>>>(x2, 256, views_b, 32, 256, 0,
      NF, NF, NF, NF, wt_rgb1, 288, b_rgb1, xr, 256, 0, 0, 0, NFW, NFW);
  rgb2_kernel<<<gStat, blk, 0, stream>>>(xr, w_rgb2, b_rgb2, out_rgb);
}